// Round 9
// baseline (522.165 us; speedup 1.0000x reference)
//
#include <hip/hip_runtime.h>
#include <math.h>

typedef short short8 __attribute__((ext_vector_type(8)));
typedef float float4v __attribute__((ext_vector_type(4)));
#define AS1 __attribute__((address_space(1)))
#define AS3 __attribute__((address_space(3)))

__device__ __forceinline__ float b2f(ushort u) {
    unsigned v = ((unsigned)u) << 16; float f; __builtin_memcpy(&f, &v, 4); return f;
}
__device__ __forceinline__ ushort f2b(float f) {
    unsigned v; __builtin_memcpy(&v, &f, 4);
    unsigned r = (v + 0x7fffu + ((v >> 16) & 1u)) >> 16;
    return (ushort)r;
}

// ---------- fp32 -> bf16 convert with optional scale (and zero-pad rows) ----------
__global__ void cvt_pad(const float* __restrict__ src, ushort* __restrict__ dst,
                        int src_rows, int cols, int total4, float scl) {
    int i = blockIdx.x * 256 + threadIdx.x;
    if (i >= total4) return;
    size_t e = (size_t)i * 4;
    int r = (int)(e / (size_t)cols);
    ushort4 o;
    if (r < src_rows) {
        float4 v = *(const float4*)(src + e);
        o.x = f2b(v.x * scl); o.y = f2b(v.y * scl); o.z = f2b(v.z * scl); o.w = f2b(v.w * scl);
    } else {
        o.x = 0; o.y = 0; o.z = 0; o.w = 0;
    }
    *(ushort4*)(dst + e) = o;
}

// ---------- bf16 GEMM: C(MxN) = A(MxK) @ B(NxK)^T, strided ----------
// mode 0: bf16 C; mode 1: f32 C; mode 2: MLA kv scatter (Kf nope cols + Vt transposed V)
__global__ __launch_bounds__(256)
void gemm_bt(const ushort* __restrict__ A, const ushort* __restrict__ B,
             void* __restrict__ Cv, int K, int lda, int ldb, int ldc, int mode,
             ushort* __restrict__ Kf, ushort* __restrict__ Vtp) {
    __shared__ ushort sA[128 * 32];
    __shared__ ushort sB[128 * 32];
    const int tid = threadIdx.x;
    const int wave = tid >> 6, lane = tid & 63;
    const int bm = blockIdx.y * 128, bn = blockIdx.x * 128;
    const int wm = (wave >> 1) * 64, wn = (wave & 1) * 64;
    const int lq = lane & 15, quad = lane >> 4;
    float4v acc[4][4] = {};

    const int srow = wave * 32 + (lane >> 2);
    const int skc = (lane & 3) * 8;
    const ushort* Ag = A + (size_t)(bm + srow) * lda + skc;
    const ushort* Bg = B + (size_t)(bn + srow) * ldb + skc;
    ushort* sAw = sA + (wave * 32) * 32;
    ushort* sBw = sB + (wave * 32) * 32;

    for (int k0 = 0; k0 < K; k0 += 32) {
        __builtin_amdgcn_global_load_lds((const AS1 void*)(Ag + k0), (AS3 void*)sAw, 16, 0, 0);
        __builtin_amdgcn_global_load_lds((const AS1 void*)(Ag + (size_t)16 * lda + k0),
                                         (AS3 void*)(sAw + 16 * 32), 16, 0, 0);
        __builtin_amdgcn_global_load_lds((const AS1 void*)(Bg + k0), (AS3 void*)sBw, 16, 0, 0);
        __builtin_amdgcn_global_load_lds((const AS1 void*)(Bg + (size_t)16 * ldb + k0),
                                         (AS3 void*)(sBw + 16 * 32), 16, 0, 0);
        __syncthreads();
        short8 af[4], bfr[4];
#pragma unroll
        for (int i = 0; i < 4; ++i) {
            af[i]  = *(const short8*)(sA + (wm + i * 16 + lq) * 32 + quad * 8);
            bfr[i] = *(const short8*)(sB + (wn + i * 16 + lq) * 32 + quad * 8);
        }
#pragma unroll
        for (int i = 0; i < 4; ++i)
#pragma unroll
            for (int j = 0; j < 4; ++j)
                acc[i][j] = __builtin_amdgcn_mfma_f32_16x16x32_bf16(af[i], bfr[j], acc[i][j], 0, 0, 0);
        __syncthreads();
    }
#pragma unroll
    for (int i = 0; i < 4; ++i) {
        int row0 = bm + wm + i * 16 + quad * 4;
#pragma unroll
        for (int j = 0; j < 4; ++j) {
            int col = bn + wn + j * 16 + lq;
            if (mode == 0) {
                ushort* C = (ushort*)Cv;
#pragma unroll
                for (int r = 0; r < 4; ++r)
                    C[(size_t)(row0 + r) * ldc + col] = f2b(acc[i][j][r]);
            } else if (mode == 1) {
                float* C = (float*)Cv;
#pragma unroll
                for (int r = 0; r < 4; ++r)
                    C[(size_t)(row0 + r) * ldc + col] = acc[i][j][r];
            } else {
                // MLA kv scatter: col = h*256 + c; c<128 -> Kfull nope, else Vt transposed
                int h = col >> 8, c = col & 255;
                int bh = ((row0 >> 11) << 4) + h;
                if (c < 128) {
#pragma unroll
                    for (int r = 0; r < 4; ++r) {
                        int s = (row0 + r) & 2047;
                        Kf[((size_t)bh * 2048 + s) * 200 + c] = f2b(acc[i][j][r]);
                    }
                } else {
                    int d = c - 128;
                    int kt = (row0 & 2047) >> 6, kv = row0 & 63;
                    ushort4 o;
                    o.x = f2b(acc[i][j][0]); o.y = f2b(acc[i][j][1]);
                    o.z = f2b(acc[i][j][2]); o.w = f2b(acc[i][j][3]);
                    *(ushort4*)(Vtp + (((size_t)bh * 32 + kt) * 128 + d) * 72 + kv) = o;
                }
            }
        }
    }
}

// ---------- rmsnorm (in-place, one block per row, strided) ----------
__global__ void rmsnorm_inplace(ushort* __restrict__ d, const float* __restrict__ w,
                                int cols, int ld) {
    int row = blockIdx.x, tid = threadIdx.x;
    ushort* p = d + (size_t)row * ld;
    float ss = 0.f;
    for (int i = tid; i < cols; i += 256) { float v = b2f(p[i]); ss += v * v; }
#pragma unroll
    for (int off = 32; off >= 1; off >>= 1) ss += __shfl_xor(ss, off);
    __shared__ float red[4];
    if ((tid & 63) == 0) red[tid >> 6] = ss;
    __syncthreads();
    float tot = red[0] + red[1] + red[2] + red[3];
    float rs = rsqrtf(tot / (float)cols + 1e-6f);
    for (int i = tid; i < cols; i += 256) p[i] = f2b(b2f(p[i]) * rs * w[i]);
}

// ---------- kv norm (cols 0..512) + k_pe rope (cols 512..576), strided ----------
__global__ void kvnorm_rope(const ushort* __restrict__ kvraw, const float* __restrict__ w,
                            const float* __restrict__ freqs, ushort* __restrict__ kvc,
                            ushort* __restrict__ kpe, int ld) {
    int row = blockIdx.x, tid = threadIdx.x;
    int s = row & 2047;
    const ushort* p = kvraw + (size_t)row * ld;
    float v0 = b2f(p[tid]), v1 = b2f(p[tid + 256]);
    float ss = v0 * v0 + v1 * v1;
#pragma unroll
    for (int off = 32; off >= 1; off >>= 1) ss += __shfl_xor(ss, off);
    __shared__ float red[4];
    if ((tid & 63) == 0) red[tid >> 6] = ss;
    __syncthreads();
    float tot = red[0] + red[1] + red[2] + red[3];
    float rs = rsqrtf(tot / 512.f + 1e-6f);
    kvc[(size_t)row * 512 + tid] = f2b(v0 * rs * w[tid]);
    kvc[(size_t)row * 512 + tid + 256] = f2b(v1 * rs * w[tid + 256]);
    if (tid < 32) {
        float re = b2f(p[512 + 2 * tid]), im = b2f(p[512 + 2 * tid + 1]);
        float cs = freqs[(s * 32 + tid) * 2], sn = freqs[(s * 32 + tid) * 2 + 1];
        kpe[(size_t)row * 64 + 2 * tid] = f2b(re * cs - im * sn);
        kpe[(size_t)row * 64 + 2 * tid + 1] = f2b(re * sn + im * cs);
    }
}

// ---------- rope on q_pe (last 64 of each 192-dim head) ----------
__global__ void qrope(ushort* __restrict__ q, const float* __restrict__ freqs) {
    int idx = blockIdx.x * 256 + threadIdx.x;
    int i = idx & 31;
    int h = (idx >> 5) & 15;
    int srow = idx >> 9;
    int s = srow & 2047;
    ushort* p = q + ((size_t)srow * 16 + h) * 192 + 128 + 2 * i;
    float re = b2f(p[0]), im = b2f(p[1]);
    float cs = freqs[(s * 32 + i) * 2], sn = freqs[(s * 32 + i) * 2 + 1];
    p[0] = f2b(re * cs - im * sn);
    p[1] = f2b(re * sn + im * cs);
}

// ---------- fill roped k_pe into Kfull cols 128..191 (broadcast over h) ----------
__global__ void kpe_fill(const ushort* __restrict__ kpe, ushort* __restrict__ Kfull) {
    int tid = threadIdx.x;
    int row = blockIdx.x * 8 + (tid >> 5);   // row = bh*2048 + s
    int c = tid & 31;
    int bh = row >> 11, s = row & 2047, b = bh >> 4;
    ushort2 v;
    v.x = kpe[((size_t)b * 2048 + s) * 64 + 2 * c];
    v.y = kpe[((size_t)b * 2048 + s) * 64 + 2 * c + 1];
    *(ushort2*)(Kfull + (size_t)row * 200 + 128 + 2 * c) = v;
}

// ---------- causal flash attention: R6 per-tile schedule + balanced pairing ----------
// R8 isolated setprio+V-hoist = -15us -> reverted; R6's stage->drain->compute
// per-tile body is a local optimum, kept VERBATIM. Only change vs R6: the decode.
// R6 decode paired CU c with st and st-8 -> per-CU tile sums 48(worst)..20(best),
// makespan-bound on CU 0. Complementary pairing (t<8 ? 15-t : t-8) makes every
// CU's two blocks sum to exactly 36 tiles (st + (15-st)). R7 tested this decode
// confounded with dbuf (which R8's FIFO analysis showed was the regression);
// this round isolates the pairing on the pristine R6 body.
__global__ __launch_bounds__(512, 2)
void mla_attn12(const ushort* __restrict__ q, const ushort* __restrict__ Kfull,
                const ushort* __restrict__ Vt, ushort* __restrict__ out) {
    __shared__ ushort sK[64 * 200];
    __shared__ ushort sP[8][16][72];
    const int tid = threadIdx.x, wave = tid >> 6, lane = tid & 63;
    const int lq = lane & 15, quad = lane >> 4;
    const int lin = blockIdx.x;
    const int e = lin & 7, idx = lin >> 3;
    const int t = idx >> 2;
    const int st = (t < 8) ? (15 - t) : (t - 8);   // CU pair sums to 36 tiles
    const int bh = e + 8 * (idx & 3);              // XCD-pinned: bh%8 == lin%8
    const int b = bh >> 4, h = bh & 15;
    const ushort* Kb = Kfull + (size_t)bh * 2048 * 200;
    const ushort* Vb = Vt + (size_t)bh * 32 * 128 * 72;

    const int qrow = st * 128 + wave * 16 + lq;
    const ushort* qp = q + ((size_t)(b * 2048 + qrow) * 16 + h) * 192 + quad * 8;
    short8 qf[6];
#pragma unroll
    for (int c = 0; c < 6; ++c) qf[c] = *(const short8*)(qp + c * 32);

    float4v oacc[8] = {};
    float m_i[4] = {-INFINITY, -INFINITY, -INFINITY, -INFINITY};
    float l_i[4] = {0.f, 0.f, 0.f, 0.f};
    const int myrow0 = st * 128 + wave * 16 + quad * 4;
    const int ktmax = 2 * st + 1;

    for (int kt = 0; kt <= ktmax; ++kt) {
        // stage K tile (64x200 = 1600 16B-chunks) across all 512 threads
        const ushort* Ksrc = Kb + (size_t)kt * 64 * 200;
#pragma unroll
        for (int i = 0; i < 4; ++i) {
            int cb = i * 512 + wave * 64;    // wave-uniform chunk base
            if (cb < 1600)
                __builtin_amdgcn_global_load_lds((const AS1 void*)(Ksrc + (size_t)(cb + lane) * 8),
                                                 (AS3 void*)(sK + cb * 8), 16, 0, 0);
        }
        __syncthreads();
        const ushort* Vrow = Vb + (size_t)kt * 128 * 72 + (size_t)lq * 72 + quad * 8;
        // S = Q K^T (per wave: 16 x 64)
        float4v sc[4];
#pragma unroll
        for (int ct = 0; ct < 4; ++ct) {
            float4v a = {0.f, 0.f, 0.f, 0.f};
#pragma unroll
            for (int c = 0; c < 6; ++c) {
                short8 kf = *(const short8*)(sK + (ct * 16 + lq) * 200 + c * 32 + quad * 8);
                a = __builtin_amdgcn_mfma_f32_16x16x32_bf16(qf[c], kf, a, 0, 0, 0);
            }
            sc[ct] = a;
        }
        // hoist V loads for kc=0 from L2: independent, fly during softmax
        short8 vf0[8];
#pragma unroll
        for (int dt = 0; dt < 8; ++dt)
            vf0[dt] = *(const short8*)(Vrow + (size_t)dt * 16 * 72);
        // causal mask (branchless) + online softmax (base-2, scores pre-scaled)
        float mnew[4];
#pragma unroll
        for (int r = 0; r < 4; ++r) mnew[r] = m_i[r];
#pragma unroll
        for (int ct = 0; ct < 4; ++ct)
#pragma unroll
            for (int r = 0; r < 4; ++r) {
                float v = (kt * 64 + ct * 16 + lq) > (myrow0 + r) ? -INFINITY : sc[ct][r];
                sc[ct][r] = v;
                mnew[r] = fmaxf(mnew[r], v);
            }
#pragma unroll
        for (int off = 8; off >= 1; off >>= 1)
#pragma unroll
            for (int r = 0; r < 4; ++r) mnew[r] = fmaxf(mnew[r], __shfl_xor(mnew[r], off));
        // defer-max: rescale only if the max grew by > 8 (log2 domain)
        float g = mnew[0] - m_i[0];
#pragma unroll
        for (int r = 1; r < 4; ++r) g = fmaxf(g, mnew[r] - m_i[r]);
        if (__ballot(g > 8.0f) != 0ull) {
#pragma unroll
            for (int r = 0; r < 4; ++r) {
                float a = __builtin_amdgcn_exp2f(m_i[r] - mnew[r]);
                m_i[r] = mnew[r];
                l_i[r] *= a;
#pragma unroll
                for (int dt = 0; dt < 8; ++dt) oacc[dt][r] *= a;
            }
        }
        float psum[4] = {0.f, 0.f, 0.f, 0.f};
#pragma unroll
        for (int ct = 0; ct < 4; ++ct)
#pragma unroll
            for (int r = 0; r < 4; ++r) {
                float pv = __builtin_amdgcn_exp2f(sc[ct][r] - m_i[r]);
                psum[r] += pv;
                sP[wave][quad * 4 + r][ct * 16 + lq] = f2b(pv);
            }
#pragma unroll
        for (int off = 8; off >= 1; off >>= 1)
#pragma unroll
            for (int r = 0; r < 4; ++r) psum[r] += __shfl_xor(psum[r], off);
#pragma unroll
        for (int r = 0; r < 4; ++r) l_i[r] += psum[r];
        // O += P @ V (sP wave-private: same-wave DS order suffices; V from L2)
#pragma unroll
        for (int kc = 0; kc < 2; ++kc) {
            short8 pf = *(const short8*)(&sP[wave][lq][kc * 32 + quad * 8]);
#pragma unroll
            for (int dt = 0; dt < 8; ++dt) {
                short8 vf = kc == 0 ? vf0[dt]
                                    : *(const short8*)(Vrow + (size_t)dt * 16 * 72 + 32);
                oacc[dt] = __builtin_amdgcn_mfma_f32_16x16x32_bf16(pf, vf, oacc[dt], 0, 0, 0);
            }
        }
        __syncthreads();   // protect sK before next stage
    }
    float inv[4];
#pragma unroll
    for (int r = 0; r < 4; ++r) inv[r] = 1.f / l_i[r];
#pragma unroll
    for (int dt = 0; dt < 8; ++dt) {
#pragma unroll
        for (int r = 0; r < 4; ++r) {
            out[((size_t)(b * 2048 + myrow0 + r) * 16 + h) * 128 + dt * 16 + lq] =
                f2b(oacc[dt][r] * inv[r]);
        }
    }
}

// ---------- launch ----------
extern "C" void kernel_launch(void* const* d_in, const int* in_sizes, int n_in,
                              void* d_out, int out_size, void* d_ws, size_t ws_size,
                              hipStream_t stream) {
    const float* x     = (const float*)d_in[0];
    const float* freqs = (const float*)d_in[2];
    const float* wq_a  = (const float*)d_in[3];
    const float* qnw   = (const float*)d_in[4];
    const float* wq_b  = (const float*)d_in[5];
    const float* wkv_a = (const float*)d_in[6];
    const float* kvnw  = (const float*)d_in[7];
    const float* wkv_b = (const float*)d_in[8];
    const float* wo    = (const float*)d_in[9];

    char* ws = (char*)d_ws;
    size_t off = 0;
    auto alloc = [&](size_t n) { char* p = ws + off; off += (n + 255) & ~(size_t)255; return p; };
    ushort* xb    = (ushort*)alloc(4096ull * 2048 * 2);   // dead after fused a-gemm
    ushort* wqkva = (ushort*)alloc(2176ull * 2048 * 2);   // dead after fused a-gemm
    ushort* wqbb  = (ushort*)alloc(3072ull * 1536 * 2);   // dead after q_b gemm
    ushort* wkvbb = (ushort*)alloc(4096ull * 512 * 2);    // live until kv_b gemm
    ushort* wob   = (ushort*)alloc(2048ull * 2048 * 2);   // live until final gemm
    ushort* qakv  = (ushort*)alloc(4096ull * 2176 * 2);   // dead after q_b gemm
    ushort* kvc   = (ushort*)alloc(4096ull * 512 * 2);    // live until kv_b gemm
    ushort* kpe   = (ushort*)alloc(4096ull * 64 * 2);
    ushort* qfull = (ushort*)alloc(4096ull * 3072 * 2);
    ushort* kvbuf = (ushort*)alloc(4096ull * 4096 * 2);   // hosts Kfull (26.2 <= 33.6 MB)
    ushort* attno = (ushort*)alloc(4096ull * 2048 * 2);
    if (off > ws_size) return;
    // Kfull[32][2048][200] in kvbuf region (no aliasing).
    ushort* Kfull = kvbuf;
    // Vt[32][32][128][72] = 18.9 MB over xb+wqkva (25.7 MB), both dead before kv_b gemm.
    ushort* Vt = xb;

    auto cvt = [&](const float* s, ushort* dd, int sr, int cols, size_t dtot, float scl) {
        int t4 = (int)(dtot / 4);
        cvt_pad<<<(t4 + 255) / 256, 256, 0, stream>>>(s, dd, sr, cols, t4, scl);
    };
    // bake softmax_scale * log2(e) into wq_b so attn scores land pre-scaled in log2 domain
    const float qk_scale = 1.44269504f / sqrtf(192.0f);
    cvt(x, xb, 4096, 2048, 4096ull * 2048, 1.f);
    cvt(wq_a, wqkva, 1536, 2048, 1536ull * 2048, 1.f);
    cvt(wkv_a, wqkva + 1536ull * 2048, 576, 2048, 640ull * 2048, 1.f);
    cvt(wq_b, wqbb, 3072, 1536, 3072ull * 1536, qk_scale);
    cvt(wkv_b, wkvbb, 4096, 512, 4096ull * 512, 1.f);
    cvt(wo, wob, 2048, 2048, 2048ull * 2048, 1.f);

    // fused q_a + kv_a projection: [4096 x 2048] @ [2176 x 2048]^T
    gemm_bt<<<dim3(17, 32), 256, 0, stream>>>(xb, wqkva, qakv, 2048, 2048, 2048, 2176, 0, nullptr, nullptr);
    rmsnorm_inplace<<<4096, 256, 0, stream>>>(qakv, qnw, 1536, 2176);
    kvnorm_rope<<<4096, 256, 0, stream>>>(qakv + 1536, kvnw, freqs, kvc, kpe, 2176);
    gemm_bt<<<dim3(24, 32), 256, 0, stream>>>(qakv, wqbb, qfull, 1536, 2176, 1536, 3072, 0, nullptr, nullptr);
    qrope<<<8192, 256, 0, stream>>>(qfull, freqs);
    kpe_fill<<<8192, 256, 0, stream>>>(kpe, Kfull);
    // kv_b gemm with fused scatter epilogue: writes Kfull nope cols + transposed Vt
    // (xb/wqkva dead -> Vt region safe; qakv dead)
    gemm_bt<<<dim3(32, 32), 256, 0, stream>>>(kvc, wkvbb, nullptr, 512, 512, 512, 0, 2, Kfull, Vt);
    mla_attn12<<<dim3(512), 512, 0, stream>>>(qfull, Kfull, Vt, attno);
    gemm_bt<<<dim3(16, 32), 256, 0, stream>>>(attno, wob, (float*)d_out, 2048, 2048, 2048, 2048, 1, nullptr, nullptr);
}

// Round 10
// 493.612 us; speedup vs baseline: 1.0578x; 1.0578x over previous
//
#include <hip/hip_runtime.h>
#include <math.h>

typedef short short8 __attribute__((ext_vector_type(8)));
typedef float float4v __attribute__((ext_vector_type(4)));
#define AS1 __attribute__((address_space(1)))
#define AS3 __attribute__((address_space(3)))

__device__ __forceinline__ float b2f(ushort u) {
    unsigned v = ((unsigned)u) << 16; float f; __builtin_memcpy(&f, &v, 4); return f;
}
__device__ __forceinline__ ushort f2b(float f) {
    unsigned v; __builtin_memcpy(&v, &f, 4);
    unsigned r = (v + 0x7fffu + ((v >> 16) & 1u)) >> 16;
    return (ushort)r;
}

// ---------- fp32 -> bf16 convert with optional scale (and zero-pad rows) ----------
__global__ void cvt_pad(const float* __restrict__ src, ushort* __restrict__ dst,
                        int src_rows, int cols, int total4, float scl) {
    int i = blockIdx.x * 256 + threadIdx.x;
    if (i >= total4) return;
    size_t e = (size_t)i * 4;
    int r = (int)(e / (size_t)cols);
    ushort4 o;
    if (r < src_rows) {
        float4 v = *(const float4*)(src + e);
        o.x = f2b(v.x * scl); o.y = f2b(v.y * scl); o.z = f2b(v.z * scl); o.w = f2b(v.w * scl);
    } else {
        o.x = 0; o.y = 0; o.z = 0; o.w = 0;
    }
    *(ushort4*)(dst + e) = o;
}

// ---------- bf16 GEMM: C(MxN) = A(MxK) @ B(NxK)^T, strided (m97-structure) ----------
// mode 0: bf16 C; mode 1: f32 C; mode 2: MLA kv scatter (Kf nope cols + Vt transposed V)
__global__ __launch_bounds__(256)
void gemm_bt(const ushort* __restrict__ A, const ushort* __restrict__ B,
             void* __restrict__ Cv, int K, int lda, int ldb, int ldc, int mode,
             ushort* __restrict__ Kf, ushort* __restrict__ Vtp) {
    __shared__ ushort sA[128 * 32];
    __shared__ ushort sB[128 * 32];
    const int tid = threadIdx.x;
    const int wave = tid >> 6, lane = tid & 63;
    const int bm = blockIdx.y * 128, bn = blockIdx.x * 128;
    const int wm = (wave >> 1) * 64, wn = (wave & 1) * 64;
    const int lq = lane & 15, quad = lane >> 4;
    float4v acc[4][4] = {};

    const int srow = wave * 32 + (lane >> 2);
    const int skc = (lane & 3) * 8;
    const ushort* Ag = A + (size_t)(bm + srow) * lda + skc;
    const ushort* Bg = B + (size_t)(bn + srow) * ldb + skc;
    ushort* sAw = sA + (wave * 32) * 32;
    ushort* sBw = sB + (wave * 32) * 32;

    for (int k0 = 0; k0 < K; k0 += 32) {
        __builtin_amdgcn_global_load_lds((const AS1 void*)(Ag + k0), (AS3 void*)sAw, 16, 0, 0);
        __builtin_amdgcn_global_load_lds((const AS1 void*)(Ag + (size_t)16 * lda + k0),
                                         (AS3 void*)(sAw + 16 * 32), 16, 0, 0);
        __builtin_amdgcn_global_load_lds((const AS1 void*)(Bg + k0), (AS3 void*)sBw, 16, 0, 0);
        __builtin_amdgcn_global_load_lds((const AS1 void*)(Bg + (size_t)16 * ldb + k0),
                                         (AS3 void*)(sBw + 16 * 32), 16, 0, 0);
        __syncthreads();
        short8 af[4], bfr[4];
#pragma unroll
        for (int i = 0; i < 4; ++i) {
            af[i]  = *(const short8*)(sA + (wm + i * 16 + lq) * 32 + quad * 8);
            bfr[i] = *(const short8*)(sB + (wn + i * 16 + lq) * 32 + quad * 8);
        }
#pragma unroll
        for (int i = 0; i < 4; ++i)
#pragma unroll
            for (int j = 0; j < 4; ++j)
                acc[i][j] = __builtin_amdgcn_mfma_f32_16x16x32_bf16(af[i], bfr[j], acc[i][j], 0, 0, 0);
        __syncthreads();
    }
#pragma unroll
    for (int i = 0; i < 4; ++i) {
        int row0 = bm + wm + i * 16 + quad * 4;
#pragma unroll
        for (int j = 0; j < 4; ++j) {
            int col = bn + wn + j * 16 + lq;
            if (mode == 0) {
                ushort* C = (ushort*)Cv;
#pragma unroll
                for (int r = 0; r < 4; ++r)
                    C[(size_t)(row0 + r) * ldc + col] = f2b(acc[i][j][r]);
            } else if (mode == 1) {
                float* C = (float*)Cv;
#pragma unroll
                for (int r = 0; r < 4; ++r)
                    C[(size_t)(row0 + r) * ldc + col] = acc[i][j][r];
            } else {
                int h = col >> 8, c = col & 255;
                int bh = ((row0 >> 11) << 4) + h;
                if (c < 128) {
#pragma unroll
                    for (int r = 0; r < 4; ++r) {
                        int s = (row0 + r) & 2047;
                        Kf[((size_t)bh * 2048 + s) * 200 + c] = f2b(acc[i][j][r]);
                    }
                } else {
                    int d = c - 128;
                    int kt = (row0 & 2047) >> 6, kv = row0 & 63;
                    ushort4 o;
                    o.x = f2b(acc[i][j][0]); o.y = f2b(acc[i][j][1]);
                    o.z = f2b(acc[i][j][2]); o.w = f2b(acc[i][j][3]);
                    *(ushort4*)(Vtp + (((size_t)bh * 32 + kt) * 128 + d) * 72 + kv) = o;
                }
            }
        }
    }
}

// ---------- 256x256 8-phase bf16 GEMM (T2 swizzle + T3/T4 counted vmcnt + T5) ----------
// C(MxN) = A(MxK) @ B(NxK)^T. Requires M%256==0, N%256==0, K%128==0, grid%8==0.
// Schedule (derived from the m201 template, linear-dest gload_lds + pre-swizzled src):
//   iter j computes tiles 2j (buf0, phases 1-4) and 2j+1 (buf1, phases 5-8).
//   B-frags of a tile are ds_read ONCE (phase 1/5, 8 reads) and held in regs; A-quadrant
//   (4 reads) per phase. Stage 1 half-tile per phase into regions freed by the barrier
//   structure: p1,p2 -> A(2j+1)->buf1 ; p3,p4 -> B(2j+2)->buf0 ; p5,p6 -> A(2j+2)->buf0 ;
//   p7,p8 -> B(2j+3)->buf1. Counted s_waitcnt vmcnt(4) ONLY at p4/p8 (vmcnt(0) on the
//   last iter, where future-tile stages are skipped and the count would be wrong).
// Swizzle (rule #21, both-sides): LDS dest linear; global SRC permuted by the st
//   involution l = x ^ (((x>>9)&1)<<5); every ds_read XORs its byte offset the same way.
__device__ __forceinline__ short8 rdf(const ushort* base, int row, int kb) {
    int raw = row * 128 + kb;
    int off = raw ^ (((raw >> 9) & 1) << 5);
    return *(const short8*)((const char*)base + off);
}
__device__ __forceinline__ void stage_half(const ushort* __restrict__ G, int ldg,
                                           int row0, int k0, ushort* ldsbase,
                                           int wave, int lane) {
#pragma unroll
    for (int rr = 0; rr < 2; ++rr) {
        int x = rr * 8192 + wave * 1024 + lane * 16;   // this thread's linear dst byte
        int l = x ^ (((x >> 9) & 1) << 5);             // logical byte it must hold
        int r = l >> 7, c2 = l & 127;
        __builtin_amdgcn_global_load_lds(
            (const AS1 void*)(G + (size_t)(row0 + r) * ldg + k0 + (c2 >> 1)),
            (AS3 void*)((char*)ldsbase + rr * 8192 + wave * 1024), 16, 0, 0);
    }
}

#define GBAR() do { asm volatile("" ::: "memory"); __builtin_amdgcn_s_barrier(); } while (0)

#define PHASE(QD, SB, VMTAIL, ...) do {                                               \
    short8 a0  = rdf(&sA[SB][0], wm * 128 + (2 * (QD)) * 16 + lq, quad * 16);         \
    short8 a0k = rdf(&sA[SB][0], wm * 128 + (2 * (QD)) * 16 + lq, 64 + quad * 16);    \
    short8 a1  = rdf(&sA[SB][0], wm * 128 + (2 * (QD) + 1) * 16 + lq, quad * 16);     \
    short8 a1k = rdf(&sA[SB][0], wm * 128 + (2 * (QD) + 1) * 16 + lq, 64 + quad * 16);\
    if ((QD) == 0) {                                                                  \
        _Pragma("unroll")                                                             \
        for (int fc = 0; fc < 4; ++fc) {                                              \
            bF[fc][0] = rdf(&sB[SB][0], wn * 64 + fc * 16 + lq, quad * 16);           \
            bF[fc][1] = rdf(&sB[SB][0], wn * 64 + fc * 16 + lq, 64 + quad * 16);      \
        }                                                                             \
    }                                                                                 \
    __VA_ARGS__;                                                                      \
    GBAR();                                                                           \
    __builtin_amdgcn_s_setprio(1);                                                    \
    _Pragma("unroll")                                                                 \
    for (int fc = 0; fc < 4; ++fc) {                                                  \
        acc[2*(QD)][fc]   = __builtin_amdgcn_mfma_f32_16x16x32_bf16(a0,  bF[fc][0], acc[2*(QD)][fc],   0, 0, 0); \
        acc[2*(QD)][fc]   = __builtin_amdgcn_mfma_f32_16x16x32_bf16(a0k, bF[fc][1], acc[2*(QD)][fc],   0, 0, 0); \
        acc[2*(QD)+1][fc] = __builtin_amdgcn_mfma_f32_16x16x32_bf16(a1,  bF[fc][0], acc[2*(QD)+1][fc], 0, 0, 0); \
        acc[2*(QD)+1][fc] = __builtin_amdgcn_mfma_f32_16x16x32_bf16(a1k, bF[fc][1], acc[2*(QD)+1][fc], 0, 0, 0); \
    }                                                                                 \
    __builtin_amdgcn_s_setprio(0);                                                    \
    VMTAIL;                                                                           \
    GBAR();                                                                           \
} while (0)

__global__ __launch_bounds__(512, 2)
void gemm8p(const ushort* __restrict__ A, const ushort* __restrict__ B,
            void* __restrict__ Cv, int K, int lda, int ldb, int ldc, int mode, int nbn) {
    __shared__ ushort sA[2][256 * 64];
    __shared__ ushort sB[2][256 * 64];
    const int tid = threadIdx.x, wave = tid >> 6, lane = tid & 63;
    const int lq = lane & 15, quad = lane >> 4;
    const int wm = wave >> 2, wn = wave & 3;
    const int nwg = gridDim.x;
    const int wg = (blockIdx.x & 7) * (nwg >> 3) + (blockIdx.x >> 3);  // XCD swizzle
    const int bm = (wg / nbn) * 256, bn = (wg % nbn) * 256;

    ushort* sA0h0 = &sA[0][0];     ushort* sA0h1 = &sA[0][8192];
    ushort* sA1h0 = &sA[1][0];     ushort* sA1h1 = &sA[1][8192];
    ushort* sB0h0 = &sB[0][0];     ushort* sB0h1 = &sB[0][8192];
    ushort* sB1h0 = &sB[1][0];     ushort* sB1h1 = &sB[1][8192];

    float4v acc[8][4] = {};
    const int nkt = K >> 6;        // 64-wide K tiles (even; K%128==0)
    const int iters = nkt >> 1;

    // prologue: tile0 (A+B -> buf0), tile1 B -> buf1 (tile1 A staged in iter0 p1,p2)
    stage_half(A, lda, bm,       0, sA0h0, wave, lane);
    stage_half(A, lda, bm + 128, 0, sA0h1, wave, lane);
    stage_half(B, ldb, bn,       0, sB0h0, wave, lane);
    stage_half(B, ldb, bn + 128, 0, sB0h1, wave, lane);
    stage_half(B, ldb, bn,      64, sB1h0, wave, lane);
    stage_half(B, ldb, bn + 128,64, sB1h1, wave, lane);
    asm volatile("s_waitcnt vmcnt(4)" ::: "memory");   // tile0 landed; tile1-B in flight
    GBAR();

    for (int j = 0; j < iters; ++j) {
        const int t1 = 2 * j + 1, t2 = 2 * j + 2, t3 = 2 * j + 3;
        const bool lastj = (j == iters - 1);
        short8 bF[4][2];
        // phases 1-4: tile 2j from buf0
        PHASE(0, 0, (void)0, stage_half(A, lda, bm,       t1 * 64, sA1h0, wave, lane));
        PHASE(1, 0, (void)0, stage_half(A, lda, bm + 128, t1 * 64, sA1h1, wave, lane));
        PHASE(2, 0, (void)0, if (t2 < nkt) stage_half(B, ldb, bn,       t2 * 64, sB0h0, wave, lane));
        PHASE(3, 0,
              if (lastj) { asm volatile("s_waitcnt vmcnt(0)" ::: "memory"); }
              else       { asm volatile("s_waitcnt vmcnt(4)" ::: "memory"); },
              if (t2 < nkt) stage_half(B, ldb, bn + 128, t2 * 64, sB0h1, wave, lane));
        // phases 5-8: tile 2j+1 from buf1
        PHASE(0, 1, (void)0, if (t2 < nkt) stage_half(A, lda, bm,       t2 * 64, sA0h0, wave, lane));
        PHASE(1, 1, (void)0, if (t2 < nkt) stage_half(A, lda, bm + 128, t2 * 64, sA0h1, wave, lane));
        PHASE(2, 1, (void)0, if (t3 < nkt) stage_half(B, ldb, bn,       t3 * 64, sB1h0, wave, lane));
        PHASE(3, 1,
              if (lastj) { asm volatile("s_waitcnt vmcnt(0)" ::: "memory"); }
              else       { asm volatile("s_waitcnt vmcnt(4)" ::: "memory"); },
              if (t3 < nkt) stage_half(B, ldb, bn + 128, t3 * 64, sB1h1, wave, lane));
    }

#pragma unroll
    for (int fr = 0; fr < 8; ++fr) {
        int row0 = bm + wm * 128 + fr * 16 + quad * 4;
#pragma unroll
        for (int fc = 0; fc < 4; ++fc) {
            int col = bn + wn * 64 + fc * 16 + lq;
            if (mode == 0) {
                ushort* C = (ushort*)Cv;
#pragma unroll
                for (int r = 0; r < 4; ++r)
                    C[(size_t)(row0 + r) * ldc + col] = f2b(acc[fr][fc][r]);
            } else {
                float* C = (float*)Cv;
#pragma unroll
                for (int r = 0; r < 4; ++r)
                    C[(size_t)(row0 + r) * ldc + col] = acc[fr][fc][r];
            }
        }
    }
}

// ---------- rmsnorm (in-place, one block per row, strided) ----------
__global__ void rmsnorm_inplace(ushort* __restrict__ d, const float* __restrict__ w,
                                int cols, int ld) {
    int row = blockIdx.x, tid = threadIdx.x;
    ushort* p = d + (size_t)row * ld;
    float ss = 0.f;
    for (int i = tid; i < cols; i += 256) { float v = b2f(p[i]); ss += v * v; }
#pragma unroll
    for (int off = 32; off >= 1; off >>= 1) ss += __shfl_xor(ss, off);
    __shared__ float red[4];
    if ((tid & 63) == 0) red[tid >> 6] = ss;
    __syncthreads();
    float tot = red[0] + red[1] + red[2] + red[3];
    float rs = rsqrtf(tot / (float)cols + 1e-6f);
    for (int i = tid; i < cols; i += 256) p[i] = f2b(b2f(p[i]) * rs * w[i]);
}

// ---------- kv norm (cols 0..512) + k_pe rope (cols 512..576), strided ----------
__global__ void kvnorm_rope(const ushort* __restrict__ kvraw, const float* __restrict__ w,
                            const float* __restrict__ freqs, ushort* __restrict__ kvc,
                            ushort* __restrict__ kpe, int ld) {
    int row = blockIdx.x, tid = threadIdx.x;
    int s = row & 2047;
    const ushort* p = kvraw + (size_t)row * ld;
    float v0 = b2f(p[tid]), v1 = b2f(p[tid + 256]);
    float ss = v0 * v0 + v1 * v1;
#pragma unroll
    for (int off = 32; off >= 1; off >>= 1) ss += __shfl_xor(ss, off);
    __shared__ float red[4];
    if ((tid & 63) == 0) red[tid >> 6] = ss;
    __syncthreads();
    float tot = red[0] + red[1] + red[2] + red[3];
    float rs = rsqrtf(tot / 512.f + 1e-6f);
    kvc[(size_t)row * 512 + tid] = f2b(v0 * rs * w[tid]);
    kvc[(size_t)row * 512 + tid + 256] = f2b(v1 * rs * w[tid + 256]);
    if (tid < 32) {
        float re = b2f(p[512 + 2 * tid]), im = b2f(p[512 + 2 * tid + 1]);
        float cs = freqs[(s * 32 + tid) * 2], sn = freqs[(s * 32 + tid) * 2 + 1];
        kpe[(size_t)row * 64 + 2 * tid] = f2b(re * cs - im * sn);
        kpe[(size_t)row * 64 + 2 * tid + 1] = f2b(re * sn + im * cs);
    }
}

// ---------- rope on q_pe (last 64 of each 192-dim head) ----------
__global__ void qrope(ushort* __restrict__ q, const float* __restrict__ freqs) {
    int idx = blockIdx.x * 256 + threadIdx.x;
    int i = idx & 31;
    int h = (idx >> 5) & 15;
    int srow = idx >> 9;
    int s = srow & 2047;
    ushort* p = q + ((size_t)srow * 16 + h) * 192 + 128 + 2 * i;
    float re = b2f(p[0]), im = b2f(p[1]);
    float cs = freqs[(s * 32 + i) * 2], sn = freqs[(s * 32 + i) * 2 + 1];
    p[0] = f2b(re * cs - im * sn);
    p[1] = f2b(re * sn + im * cs);
}

// ---------- fill roped k_pe into Kfull cols 128..191 (broadcast over h) ----------
__global__ void kpe_fill(const ushort* __restrict__ kpe, ushort* __restrict__ Kfull) {
    int tid = threadIdx.x;
    int row = blockIdx.x * 8 + (tid >> 5);   // row = bh*2048 + s
    int c = tid & 31;
    int bh = row >> 11, s = row & 2047, b = bh >> 4;
    ushort2 v;
    v.x = kpe[((size_t)b * 2048 + s) * 64 + 2 * c];
    v.y = kpe[((size_t)b * 2048 + s) * 64 + 2 * c + 1];
    *(ushort2*)(Kfull + (size_t)row * 200 + 128 + 2 * c) = v;
}

// ---------- causal flash attention: R6 structure VERBATIM (proven 109us) ----------
// R7 (dbuf), R8 (setprio+V-hoist), R9 (complementary pairing) all regressed ->
// this exact body+decode is the measured local optimum. R9's lesson: the (st, st-8)
// pairing keeps both co-resident blocks alive ~half the time (16 waves/CU), which
// beats sum-balanced pairing that leaves CUs single-block (8 waves) most of the run.
__global__ __launch_bounds__(512, 2)
void mla_attn9(const ushort* __restrict__ q, const ushort* __restrict__ Kfull,
               const ushort* __restrict__ Vt, ushort* __restrict__ out) {
    __shared__ ushort sK[64 * 200];
    __shared__ ushort sP[8][16][72];
    const int tid = threadIdx.x, wave = tid >> 6, lane = tid & 63;
    const int lq = lane & 15, quad = lane >> 4;
    const int lin = blockIdx.x;
    const int e = lin & 7, idx = lin >> 3;
    const int st = 15 - (idx >> 2);          // 128-row q super-tile, big first
    const int bh = e + 8 * (idx & 3);        // XCD-pinned: bh%8 == lin%8
    const int b = bh >> 4, h = bh & 15;
    const ushort* Kb = Kfull + (size_t)bh * 2048 * 200;
    const ushort* Vb = Vt + (size_t)bh * 32 * 128 * 72;

    const int qrow = st * 128 + wave * 16 + lq;
    const ushort* qp = q + ((size_t)(b * 2048 + qrow) * 16 + h) * 192 + quad * 8;
    short8 qf[6];
#pragma unroll
    for (int c = 0; c < 6; ++c) qf[c] = *(const short8*)(qp + c * 32);

    float4v oacc[8] = {};
    float m_i[4] = {-INFINITY, -INFINITY, -INFINITY, -INFINITY};
    float l_i[4] = {0.f, 0.f, 0.f, 0.f};
    const int myrow0 = st * 128 + wave * 16 + quad * 4;
    const int ktmax = 2 * st + 1;

    for (int kt = 0; kt <= ktmax; ++kt) {
        const ushort* Ksrc = Kb + (size_t)kt * 64 * 200;
#pragma unroll
        for (int i = 0; i < 4; ++i) {
            int cb = i * 512 + wave * 64;
            if (cb < 1600)
                __builtin_amdgcn_global_load_lds((const AS1 void*)(Ksrc + (size_t)(cb + lane) * 8),
                                                 (AS3 void*)(sK + cb * 8), 16, 0, 0);
        }
        __syncthreads();
        const ushort* Vrow = Vb + (size_t)kt * 128 * 72 + (size_t)lq * 72 + quad * 8;
        float4v sc[4];
#pragma unroll
        for (int ct = 0; ct < 4; ++ct) {
            float4v a = {0.f, 0.f, 0.f, 0.f};
#pragma unroll
            for (int c = 0; c < 6; ++c) {
                short8 kf = *(const short8*)(sK + (ct * 16 + lq) * 200 + c * 32 + quad * 8);
                a = __builtin_amdgcn_mfma_f32_16x16x32_bf16(qf[c], kf, a, 0, 0, 0);
            }
            sc[ct] = a;
        }
        short8 vf0[8];
#pragma unroll
        for (int dt = 0; dt < 8; ++dt)
            vf0[dt] = *(const short8*)(Vrow + (size_t)dt * 16 * 72);
        float mnew[4];
#pragma unroll
        for (int r = 0; r < 4; ++r) mnew[r] = m_i[r];
#pragma unroll
        for (int ct = 0; ct < 4; ++ct)
#pragma unroll
            for (int r = 0; r < 4; ++r) {
                float v = (kt * 64 + ct * 16 + lq) > (myrow0 + r) ? -INFINITY : sc[ct][r];
                sc[ct][r] = v;
                mnew[r] = fmaxf(mnew[r], v);
            }
#pragma unroll
        for (int off = 8; off >= 1; off >>= 1)
#pragma unroll
            for (int r = 0; r < 4; ++r) mnew[r] = fmaxf(mnew[r], __shfl_xor(mnew[r], off));
        float g = mnew[0] - m_i[0];
#pragma unroll
        for (int r = 1; r < 4; ++r) g = fmaxf(g, mnew[r] - m_i[r]);
        if (__ballot(g > 8.0f) != 0ull) {
#pragma unroll
            for (int r = 0; r < 4; ++r) {
                float a = __builtin_amdgcn_exp2f(m_i[r] - mnew[r]);
                m_i[r] = mnew[r];
                l_i[r] *= a;
#pragma unroll
                for (int dt = 0; dt < 8; ++dt) oacc[dt][r] *= a;
            }
        }
        float psum[4] = {0.f, 0.f, 0.f, 0.f};
#pragma unroll
        for (int ct = 0; ct < 4; ++ct)
#pragma unroll
            for (int r = 0; r < 4; ++r) {
                float pv = __builtin_amdgcn_exp2f(sc[ct][r] - m_i[r]);
                psum[r] += pv;
                sP[wave][quad * 4 + r][ct * 16 + lq] = f2b(pv);
            }
#pragma unroll
        for (int off = 8; off >= 1; off >>= 1)
#pragma unroll
            for (int r = 0; r < 4; ++r) psum[r] += __shfl_xor(psum[r], off);
#pragma unroll
        for (int r = 0; r < 4; ++r) l_i[r] += psum[r];
#pragma unroll
        for (int kc = 0; kc < 2; ++kc) {
            short8 pf = *(const short8*)(&sP[wave][lq][kc * 32 + quad * 8]);
#pragma unroll
            for (int dt = 0; dt < 8; ++dt) {
                short8 vf = kc == 0 ? vf0[dt]
                                    : *(const short8*)(Vrow + (size_t)dt * 16 * 72 + 32);
                oacc[dt] = __builtin_amdgcn_mfma_f32_16x16x32_bf16(pf, vf, oacc[dt], 0, 0, 0);
            }
        }
        __syncthreads();
    }
    float inv[4];
#pragma unroll
    for (int r = 0; r < 4; ++r) inv[r] = 1.f / l_i[r];
#pragma unroll
    for (int dt = 0; dt < 8; ++dt) {
#pragma unroll
        for (int r = 0; r < 4; ++r) {
            out[((size_t)(b * 2048 + myrow0 + r) * 16 + h) * 128 + dt * 16 + lq] =
                f2b(oacc[dt][r] * inv[r]);
        }
    }
}

// ---------- launch ----------
extern "C" void kernel_launch(void* const* d_in, const int* in_sizes, int n_in,
                              void* d_out, int out_size, void* d_ws, size_t ws_size,
                              hipStream_t stream) {
    const float* x     = (const float*)d_in[0];
    const float* freqs = (const float*)d_in[2];
    const float* wq_a  = (const float*)d_in[3];
    const float* qnw   = (const float*)d_in[4];
    const float* wq_b  = (const float*)d_in[5];
    const float* wkv_a = (const float*)d_in[6];
    const float* kvnw  = (const float*)d_in[7];
    const float* wkv_b = (const float*)d_in[8];
    const float* wo    = (const float*)d_in[9];

    char* ws = (char*)d_ws;
    size_t off = 0;
    auto alloc = [&](size_t n) { char* p = ws + off; off += (n + 255) & ~(size_t)255; return p; };
    ushort* xb    = (ushort*)alloc(4096ull * 2048 * 2);   // dead after fused a-gemm
    ushort* wqkva = (ushort*)alloc(2176ull * 2048 * 2);   // dead after fused a-gemm
    ushort* wqbb  = (ushort*)alloc(3072ull * 1536 * 2);   // dead after q_b gemm
    ushort* wkvbb = (ushort*)alloc(4096ull * 512 * 2);    // live until kv_b gemm
    ushort* wob   = (ushort*)alloc(2048ull * 2048 * 2);   // live until final gemm
    ushort* qakv  = (ushort*)alloc(4096ull * 2176 * 2);   // dead after q_b gemm
    ushort* kvc   = (ushort*)alloc(4096ull * 512 * 2);    // live until kv_b gemm
    ushort* kpe   = (ushort*)alloc(4096ull * 64 * 2);
    ushort* qfull = (ushort*)alloc(4096ull * 3072 * 2);
    ushort* kvbuf = (ushort*)alloc(4096ull * 4096 * 2);   // hosts Kfull (26.2 <= 33.6 MB)
    ushort* attno = (ushort*)alloc(4096ull * 2048 * 2);
    if (off > ws_size) return;
    ushort* Kfull = kvbuf;
    ushort* Vt = xb;   // Vt over xb+wqkva, both dead before kv_b gemm

    auto cvt = [&](const float* s, ushort* dd, int sr, int cols, size_t dtot, float scl) {
        int t4 = (int)(dtot / 4);
        cvt_pad<<<(t4 + 255) / 256, 256, 0, stream>>>(s, dd, sr, cols, t4, scl);
    };
    const float qk_scale = 1.44269504f / sqrtf(192.0f);
    cvt(x, xb, 4096, 2048, 4096ull * 2048, 1.f);
    cvt(wq_a, wqkva, 1536, 2048, 1536ull * 2048, 1.f);
    cvt(wkv_a, wqkva + 1536ull * 2048, 576, 2048, 640ull * 2048, 1.f);
    cvt(wq_b, wqbb, 3072, 1536, 3072ull * 1536, qk_scale);
    cvt(wkv_b, wkvbb, 4096, 512, 4096ull * 512, 1.f);
    cvt(wo, wob, 2048, 2048, 2048ull * 2048, 1.f);

    // fused q_a + kv_a projection (N=2176 not 256-divisible -> keep gemm_bt)
    gemm_bt<<<dim3(17, 32), 256, 0, stream>>>(xb, wqkva, qakv, 2048, 2048, 2048, 2176, 0, nullptr, nullptr);
    rmsnorm_inplace<<<4096, 256, 0, stream>>>(qakv, qnw, 1536, 2176);
    kvnorm_rope<<<4096, 256, 0, stream>>>(qakv + 1536, kvnw, freqs, kvc, kpe, 2176);
    // q_b projection: 4096x3072x1536 -> 8-phase template, 192 blocks
    gemm8p<<<dim3(192), 512, 0, stream>>>(qakv, wqbb, qfull, 1536, 2176, 1536, 3072, 0, 12);
    qrope<<<8192, 256, 0, stream>>>(qfull, freqs);
    kpe_fill<<<8192, 256, 0, stream>>>(kpe, Kfull);
    // kv_b gemm with fused scatter epilogue (keep gemm_bt)
    gemm_bt<<<dim3(32, 32), 256, 0, stream>>>(kvc, wkvbb, nullptr, 512, 512, 512, 0, 2, Kfull, Vt);
    mla_attn9<<<dim3(512), 512, 0, stream>>>(qfull, Kfull, Vt, attno);
    // out projection: 4096x2048x2048 f32 -> 8-phase template, 128 blocks
    gemm8p<<<dim3(128), 512, 0, stream>>>(attno, wob, (float*)d_out, 2048, 2048, 2048, 2048, 1, 8);
}

// Round 11
// 487.771 us; speedup vs baseline: 1.0705x; 1.0120x over previous
//
#include <hip/hip_runtime.h>
#include <math.h>

typedef short short8 __attribute__((ext_vector_type(8)));
typedef float float4v __attribute__((ext_vector_type(4)));
#define AS1 __attribute__((address_space(1)))
#define AS3 __attribute__((address_space(3)))

__device__ __forceinline__ float b2f(ushort u) {
    unsigned v = ((unsigned)u) << 16; float f; __builtin_memcpy(&f, &v, 4); return f;
}
__device__ __forceinline__ ushort f2b(float f) {
    unsigned v; __builtin_memcpy(&v, &f, 4);
    unsigned r = (v + 0x7fffu + ((v >> 16) & 1u)) >> 16;
    return (ushort)r;
}

// ---------- fp32 -> bf16 convert with optional scale (and zero-pad rows) ----------
__global__ void cvt_pad(const float* __restrict__ src, ushort* __restrict__ dst,
                        int src_rows, int cols, int total4, float scl) {
    int i = blockIdx.x * 256 + threadIdx.x;
    if (i >= total4) return;
    size_t e = (size_t)i * 4;
    int r = (int)(e / (size_t)cols);
    ushort4 o;
    if (r < src_rows) {
        float4 v = *(const float4*)(src + e);
        o.x = f2b(v.x * scl); o.y = f2b(v.y * scl); o.z = f2b(v.z * scl); o.w = f2b(v.w * scl);
    } else {
        o.x = 0; o.y = 0; o.z = 0; o.w = 0;
    }
    *(ushort4*)(dst + e) = o;
}

// ---------- bf16 GEMM: C(MxN) = A(MxK) @ B(NxK)^T, strided (m97-structure) ----------
// mode 0: bf16 C; mode 1: f32 C; mode 2: MLA kv scatter (Kf nope cols + Vt transposed V)
__global__ __launch_bounds__(256)
void gemm_bt(const ushort* __restrict__ A, const ushort* __restrict__ B,
             void* __restrict__ Cv, int K, int lda, int ldb, int ldc, int mode,
             ushort* __restrict__ Kf, ushort* __restrict__ Vtp) {
    __shared__ ushort sA[128 * 32];
    __shared__ ushort sB[128 * 32];
    const int tid = threadIdx.x;
    const int wave = tid >> 6, lane = tid & 63;
    const int bm = blockIdx.y * 128, bn = blockIdx.x * 128;
    const int wm = (wave >> 1) * 64, wn = (wave & 1) * 64;
    const int lq = lane & 15, quad = lane >> 4;
    float4v acc[4][4] = {};

    const int srow = wave * 32 + (lane >> 2);
    const int skc = (lane & 3) * 8;
    const ushort* Ag = A + (size_t)(bm + srow) * lda + skc;
    const ushort* Bg = B + (size_t)(bn + srow) * ldb + skc;
    ushort* sAw = sA + (wave * 32) * 32;
    ushort* sBw = sB + (wave * 32) * 32;

    for (int k0 = 0; k0 < K; k0 += 32) {
        __builtin_amdgcn_global_load_lds((const AS1 void*)(Ag + k0), (AS3 void*)sAw, 16, 0, 0);
        __builtin_amdgcn_global_load_lds((const AS1 void*)(Ag + (size_t)16 * lda + k0),
                                         (AS3 void*)(sAw + 16 * 32), 16, 0, 0);
        __builtin_amdgcn_global_load_lds((const AS1 void*)(Bg + k0), (AS3 void*)sBw, 16, 0, 0);
        __builtin_amdgcn_global_load_lds((const AS1 void*)(Bg + (size_t)16 * ldb + k0),
                                         (AS3 void*)(sBw + 16 * 32), 16, 0, 0);
        __syncthreads();
        short8 af[4], bfr[4];
#pragma unroll
        for (int i = 0; i < 4; ++i) {
            af[i]  = *(const short8*)(sA + (wm + i * 16 + lq) * 32 + quad * 8);
            bfr[i] = *(const short8*)(sB + (wn + i * 16 + lq) * 32 + quad * 8);
        }
#pragma unroll
        for (int i = 0; i < 4; ++i)
#pragma unroll
            for (int j = 0; j < 4; ++j)
                acc[i][j] = __builtin_amdgcn_mfma_f32_16x16x32_bf16(af[i], bfr[j], acc[i][j], 0, 0, 0);
        __syncthreads();
    }
#pragma unroll
    for (int i = 0; i < 4; ++i) {
        int row0 = bm + wm + i * 16 + quad * 4;
#pragma unroll
        for (int j = 0; j < 4; ++j) {
            int col = bn + wn + j * 16 + lq;
            if (mode == 0) {
                ushort* C = (ushort*)Cv;
#pragma unroll
                for (int r = 0; r < 4; ++r)
                    C[(size_t)(row0 + r) * ldc + col] = f2b(acc[i][j][r]);
            } else if (mode == 1) {
                float* C = (float*)Cv;
#pragma unroll
                for (int r = 0; r < 4; ++r)
                    C[(size_t)(row0 + r) * ldc + col] = acc[i][j][r];
            } else {
                int h = col >> 8, c = col & 255;
                int bh = ((row0 >> 11) << 4) + h;
                if (c < 128) {
#pragma unroll
                    for (int r = 0; r < 4; ++r) {
                        int s = (row0 + r) & 2047;
                        Kf[((size_t)bh * 2048 + s) * 200 + c] = f2b(acc[i][j][r]);
                    }
                } else {
                    int d = c - 128;
                    int kt = (row0 & 2047) >> 6, kv = row0 & 63;
                    ushort4 o;
                    o.x = f2b(acc[i][j][0]); o.y = f2b(acc[i][j][1]);
                    o.z = f2b(acc[i][j][2]); o.w = f2b(acc[i][j][3]);
                    *(ushort4*)(Vtp + (((size_t)bh * 32 + kt) * 128 + d) * 72 + kv) = o;
                }
            }
        }
    }
}

// ---------- 256x256 8-phase bf16 GEMM (T2 swizzle + T3/T4 counted vmcnt + T5) ----------
// (unchanged from R10 — verified correct, small net win; see R10 notes)
__device__ __forceinline__ short8 rdf(const ushort* base, int row, int kb) {
    int raw = row * 128 + kb;
    int off = raw ^ (((raw >> 9) & 1) << 5);
    return *(const short8*)((const char*)base + off);
}
__device__ __forceinline__ void stage_half(const ushort* __restrict__ G, int ldg,
                                           int row0, int k0, ushort* ldsbase,
                                           int wave, int lane) {
#pragma unroll
    for (int rr = 0; rr < 2; ++rr) {
        int x = rr * 8192 + wave * 1024 + lane * 16;   // this thread's linear dst byte
        int l = x ^ (((x >> 9) & 1) << 5);             // logical byte it must hold
        int r = l >> 7, c2 = l & 127;
        __builtin_amdgcn_global_load_lds(
            (const AS1 void*)(G + (size_t)(row0 + r) * ldg + k0 + (c2 >> 1)),
            (AS3 void*)((char*)ldsbase + rr * 8192 + wave * 1024), 16, 0, 0);
    }
}

#define GBAR() do { asm volatile("" ::: "memory"); __builtin_amdgcn_s_barrier(); } while (0)

#define PHASE(QD, SB, VMTAIL, ...) do {                                               \
    short8 a0  = rdf(&sA[SB][0], wm * 128 + (2 * (QD)) * 16 + lq, quad * 16);         \
    short8 a0k = rdf(&sA[SB][0], wm * 128 + (2 * (QD)) * 16 + lq, 64 + quad * 16);    \
    short8 a1  = rdf(&sA[SB][0], wm * 128 + (2 * (QD) + 1) * 16 + lq, quad * 16);     \
    short8 a1k = rdf(&sA[SB][0], wm * 128 + (2 * (QD) + 1) * 16 + lq, 64 + quad * 16);\
    if ((QD) == 0) {                                                                  \
        _Pragma("unroll")                                                             \
        for (int fc = 0; fc < 4; ++fc) {                                              \
            bF[fc][0] = rdf(&sB[SB][0], wn * 64 + fc * 16 + lq, quad * 16);           \
            bF[fc][1] = rdf(&sB[SB][0], wn * 64 + fc * 16 + lq, 64 + quad * 16);      \
        }                                                                             \
    }                                                                                 \
    __VA_ARGS__;                                                                      \
    GBAR();                                                                           \
    __builtin_amdgcn_s_setprio(1);                                                    \
    _Pragma("unroll")                                                                 \
    for (int fc = 0; fc < 4; ++fc) {                                                  \
        acc[2*(QD)][fc]   = __builtin_amdgcn_mfma_f32_16x16x32_bf16(a0,  bF[fc][0], acc[2*(QD)][fc],   0, 0, 0); \
        acc[2*(QD)][fc]   = __builtin_amdgcn_mfma_f32_16x16x32_bf16(a0k, bF[fc][1], acc[2*(QD)][fc],   0, 0, 0); \
        acc[2*(QD)+1][fc] = __builtin_amdgcn_mfma_f32_16x16x32_bf16(a1,  bF[fc][0], acc[2*(QD)+1][fc], 0, 0, 0); \
        acc[2*(QD)+1][fc] = __builtin_amdgcn_mfma_f32_16x16x32_bf16(a1k, bF[fc][1], acc[2*(QD)+1][fc], 0, 0, 0); \
    }                                                                                 \
    __builtin_amdgcn_s_setprio(0);                                                    \
    VMTAIL;                                                                           \
    GBAR();                                                                           \
} while (0)

__global__ __launch_bounds__(512, 2)
void gemm8p(const ushort* __restrict__ A, const ushort* __restrict__ B,
            void* __restrict__ Cv, int K, int lda, int ldb, int ldc, int mode, int nbn) {
    __shared__ ushort sA[2][256 * 64];
    __shared__ ushort sB[2][256 * 64];
    const int tid = threadIdx.x, wave = tid >> 6, lane = tid & 63;
    const int lq = lane & 15, quad = lane >> 4;
    const int wm = wave >> 2, wn = wave & 3;
    const int nwg = gridDim.x;
    const int wg = (blockIdx.x & 7) * (nwg >> 3) + (blockIdx.x >> 3);  // XCD swizzle
    const int bm = (wg / nbn) * 256, bn = (wg % nbn) * 256;

    ushort* sA0h0 = &sA[0][0];     ushort* sA0h1 = &sA[0][8192];
    ushort* sA1h0 = &sA[1][0];     ushort* sA1h1 = &sA[1][8192];
    ushort* sB0h0 = &sB[0][0];     ushort* sB0h1 = &sB[0][8192];
    ushort* sB1h0 = &sB[1][0];     ushort* sB1h1 = &sB[1][8192];

    float4v acc[8][4] = {};
    const int nkt = K >> 6;        // 64-wide K tiles (even; K%128==0)
    const int iters = nkt >> 1;

    // prologue: tile0 (A+B -> buf0), tile1 B -> buf1 (tile1 A staged in iter0 p1,p2)
    stage_half(A, lda, bm,       0, sA0h0, wave, lane);
    stage_half(A, lda, bm + 128, 0, sA0h1, wave, lane);
    stage_half(B, ldb, bn,       0, sB0h0, wave, lane);
    stage_half(B, ldb, bn + 128, 0, sB0h1, wave, lane);
    stage_half(B, ldb, bn,      64, sB1h0, wave, lane);
    stage_half(B, ldb, bn + 128,64, sB1h1, wave, lane);
    asm volatile("s_waitcnt vmcnt(4)" ::: "memory");   // tile0 landed; tile1-B in flight
    GBAR();

    for (int j = 0; j < iters; ++j) {
        const int t1 = 2 * j + 1, t2 = 2 * j + 2, t3 = 2 * j + 3;
        const bool lastj = (j == iters - 1);
        short8 bF[4][2];
        // phases 1-4: tile 2j from buf0
        PHASE(0, 0, (void)0, stage_half(A, lda, bm,       t1 * 64, sA1h0, wave, lane));
        PHASE(1, 0, (void)0, stage_half(A, lda, bm + 128, t1 * 64, sA1h1, wave, lane));
        PHASE(2, 0, (void)0, if (t2 < nkt) stage_half(B, ldb, bn,       t2 * 64, sB0h0, wave, lane));
        PHASE(3, 0,
              if (lastj) { asm volatile("s_waitcnt vmcnt(0)" ::: "memory"); }
              else       { asm volatile("s_waitcnt vmcnt(4)" ::: "memory"); },
              if (t2 < nkt) stage_half(B, ldb, bn + 128, t2 * 64, sB0h1, wave, lane));
        // phases 5-8: tile 2j+1 from buf1
        PHASE(0, 1, (void)0, if (t2 < nkt) stage_half(A, lda, bm,       t2 * 64, sA0h0, wave, lane));
        PHASE(1, 1, (void)0, if (t2 < nkt) stage_half(A, lda, bm + 128, t2 * 64, sA0h1, wave, lane));
        PHASE(2, 1, (void)0, if (t3 < nkt) stage_half(B, ldb, bn,       t3 * 64, sB1h0, wave, lane));
        PHASE(3, 1,
              if (lastj) { asm volatile("s_waitcnt vmcnt(0)" ::: "memory"); }
              else       { asm volatile("s_waitcnt vmcnt(4)" ::: "memory"); },
              if (t3 < nkt) stage_half(B, ldb, bn + 128, t3 * 64, sB1h1, wave, lane));
    }

#pragma unroll
    for (int fr = 0; fr < 8; ++fr) {
        int row0 = bm + wm * 128 + fr * 16 + quad * 4;
#pragma unroll
        for (int fc = 0; fc < 4; ++fc) {
            int col = bn + wn * 64 + fc * 16 + lq;
            if (mode == 0) {
                ushort* C = (ushort*)Cv;
#pragma unroll
                for (int r = 0; r < 4; ++r)
                    C[(size_t)(row0 + r) * ldc + col] = f2b(acc[fr][fc][r]);
            } else {
                float* C = (float*)Cv;
#pragma unroll
                for (int r = 0; r < 4; ++r)
                    C[(size_t)(row0 + r) * ldc + col] = acc[fr][fc][r];
            }
        }
    }
}

// ---------- rmsnorm (in-place, one block per row, strided) ----------
__global__ void rmsnorm_inplace(ushort* __restrict__ d, const float* __restrict__ w,
                                int cols, int ld) {
    int row = blockIdx.x, tid = threadIdx.x;
    ushort* p = d + (size_t)row * ld;
    float ss = 0.f;
    for (int i = tid; i < cols; i += 256) { float v = b2f(p[i]); ss += v * v; }
#pragma unroll
    for (int off = 32; off >= 1; off >>= 1) ss += __shfl_xor(ss, off);
    __shared__ float red[4];
    if ((tid & 63) == 0) red[tid >> 6] = ss;
    __syncthreads();
    float tot = red[0] + red[1] + red[2] + red[3];
    float rs = rsqrtf(tot / (float)cols + 1e-6f);
    for (int i = tid; i < cols; i += 256) p[i] = f2b(b2f(p[i]) * rs * w[i]);
}

// ---------- kv norm (cols 0..512) + k_pe rope (cols 512..576), strided ----------
__global__ void kvnorm_rope(const ushort* __restrict__ kvraw, const float* __restrict__ w,
                            const float* __restrict__ freqs, ushort* __restrict__ kvc,
                            ushort* __restrict__ kpe, int ld) {
    int row = blockIdx.x, tid = threadIdx.x;
    int s = row & 2047;
    const ushort* p = kvraw + (size_t)row * ld;
    float v0 = b2f(p[tid]), v1 = b2f(p[tid + 256]);
    float ss = v0 * v0 + v1 * v1;
#pragma unroll
    for (int off = 32; off >= 1; off >>= 1) ss += __shfl_xor(ss, off);
    __shared__ float red[4];
    if ((tid & 63) == 0) red[tid >> 6] = ss;
    __syncthreads();
    float tot = red[0] + red[1] + red[2] + red[3];
    float rs = rsqrtf(tot / 512.f + 1e-6f);
    kvc[(size_t)row * 512 + tid] = f2b(v0 * rs * w[tid]);
    kvc[(size_t)row * 512 + tid + 256] = f2b(v1 * rs * w[tid + 256]);
    if (tid < 32) {
        float re = b2f(p[512 + 2 * tid]), im = b2f(p[512 + 2 * tid + 1]);
        float cs = freqs[(s * 32 + tid) * 2], sn = freqs[(s * 32 + tid) * 2 + 1];
        kpe[(size_t)row * 64 + 2 * tid] = f2b(re * cs - im * sn);
        kpe[(size_t)row * 64 + 2 * tid + 1] = f2b(re * sn + im * cs);
    }
}

// ---------- rope on q_pe (last 64 of each 192-dim head) ----------
__global__ void qrope(ushort* __restrict__ q, const float* __restrict__ freqs) {
    int idx = blockIdx.x * 256 + threadIdx.x;
    int i = idx & 31;
    int h = (idx >> 5) & 15;
    int srow = idx >> 9;
    int s = srow & 2047;
    ushort* p = q + ((size_t)srow * 16 + h) * 192 + 128 + 2 * i;
    float re = b2f(p[0]), im = b2f(p[1]);
    float cs = freqs[(s * 32 + i) * 2], sn = freqs[(s * 32 + i) * 2 + 1];
    p[0] = f2b(re * cs - im * sn);
    p[1] = f2b(re * sn + im * cs);
}

// ---------- fill roped k_pe into Kfull cols 128..191 (broadcast over h) ----------
__global__ void kpe_fill(const ushort* __restrict__ kpe, ushort* __restrict__ Kfull) {
    int tid = threadIdx.x;
    int row = blockIdx.x * 8 + (tid >> 5);   // row = bh*2048 + s
    int c = tid & 31;
    int bh = row >> 11, s = row & 2047, b = bh >> 4;
    ushort2 v;
    v.x = kpe[((size_t)b * 2048 + s) * 64 + 2 * c];
    v.y = kpe[((size_t)b * 2048 + s) * 64 + 2 * c + 1];
    *(ushort2*)(Kfull + (size_t)row * 200 + 128 + 2 * c) = v;
}

// ---------- causal flash attention: R6 schedule, KVBLK 64 -> 128 (amortization) ----------
// R7/R8/R9 proved the per-tile schedule interior is a local optimum; this change
// only AMORTIZES it: each {stage burst, vmcnt drain, 2 barriers, shuffle reduce}
// now covers 128 kv instead of 64 (tile count halves, same total FLOPs; diagonal
// masking unchanged). PV runs in two sequential 64-kv halves through the same
// 16x72 sP (wave-private; same-wave DS ops execute in order -> safe reuse).
// LDS = sK 51.2K + sP 18.4K = 69.6K -> still 2 blocks/CU. Watch VGPR: sc[8] adds
// 16 regs; if VGPR_Count > 128 co-residency drops and this round regresses.
__global__ __launch_bounds__(512, 2)
void mla_attn13(const ushort* __restrict__ q, const ushort* __restrict__ Kfull,
                const ushort* __restrict__ Vt, ushort* __restrict__ out) {
    __shared__ ushort sK[128 * 200];
    __shared__ ushort sP[8][16][72];
    const int tid = threadIdx.x, wave = tid >> 6, lane = tid & 63;
    const int lq = lane & 15, quad = lane >> 4;
    const int lin = blockIdx.x;
    const int e = lin & 7, idx = lin >> 3;
    const int st = 15 - (idx >> 2);          // 128-row q super-tile, big first
    const int bh = e + 8 * (idx & 3);        // XCD-pinned: bh%8 == lin%8
    const int b = bh >> 4, h = bh & 15;
    const ushort* Kb = Kfull + (size_t)bh * 2048 * 200;
    const ushort* Vb = Vt + (size_t)bh * 32 * 128 * 72;

    const int qrow = st * 128 + wave * 16 + lq;
    const ushort* qp = q + ((size_t)(b * 2048 + qrow) * 16 + h) * 192 + quad * 8;
    short8 qf[6];
#pragma unroll
    for (int c = 0; c < 6; ++c) qf[c] = *(const short8*)(qp + c * 32);

    float4v oacc[8] = {};
    float m_i[4] = {-INFINITY, -INFINITY, -INFINITY, -INFINITY};
    float l_i[4] = {0.f, 0.f, 0.f, 0.f};
    const int myrow0 = st * 128 + wave * 16 + quad * 4;

    for (int kt = 0; kt <= st; ++kt) {
        // stage 128x200 K tile (3200 16B-chunks) across all 512 threads
        const ushort* Ksrc = Kb + (size_t)kt * 128 * 200;
#pragma unroll
        for (int i = 0; i < 7; ++i) {
            int cb = i * 512 + wave * 64;    // wave-uniform chunk base
            if (cb < 3200)
                __builtin_amdgcn_global_load_lds((const AS1 void*)(Ksrc + (size_t)(cb + lane) * 8),
                                                 (AS3 void*)(sK + cb * 8), 16, 0, 0);
        }
        __syncthreads();
        // V subtiles for this 128-kv tile (Vt is stored in 64-kv units)
        const ushort* Vs0 = Vb + (size_t)(2 * kt) * 128 * 72 + (size_t)lq * 72 + quad * 8;
        const ushort* Vs1 = Vs0 + 128 * 72;
        // S = Q K^T (per wave: 16 x 128)
        float4v sc[8];
#pragma unroll
        for (int ct = 0; ct < 8; ++ct) {
            float4v a = {0.f, 0.f, 0.f, 0.f};
#pragma unroll
            for (int c = 0; c < 6; ++c) {
                short8 kf = *(const short8*)(sK + (ct * 16 + lq) * 200 + c * 32 + quad * 8);
                a = __builtin_amdgcn_mfma_f32_16x16x32_bf16(qf[c], kf, a, 0, 0, 0);
            }
            sc[ct] = a;
        }
        // hoist V loads for half0/kc0 from L2: independent, fly during softmax
        short8 vf00[8];
#pragma unroll
        for (int dt = 0; dt < 8; ++dt)
            vf00[dt] = *(const short8*)(Vs0 + (size_t)dt * 16 * 72);
        // causal mask (branchless; only the diagonal tile actually masks) + max
        float mnew[4];
#pragma unroll
        for (int r = 0; r < 4; ++r) mnew[r] = m_i[r];
#pragma unroll
        for (int ct = 0; ct < 8; ++ct)
#pragma unroll
            for (int r = 0; r < 4; ++r) {
                float v = (kt * 128 + ct * 16 + lq) > (myrow0 + r) ? -INFINITY : sc[ct][r];
                sc[ct][r] = v;
                mnew[r] = fmaxf(mnew[r], v);
            }
#pragma unroll
        for (int off = 8; off >= 1; off >>= 1)
#pragma unroll
            for (int r = 0; r < 4; ++r) mnew[r] = fmaxf(mnew[r], __shfl_xor(mnew[r], off));
        // defer-max: rescale only if the max grew by > 8 (log2 domain)
        float g = mnew[0] - m_i[0];
#pragma unroll
        for (int r = 1; r < 4; ++r) g = fmaxf(g, mnew[r] - m_i[r]);
        if (__ballot(g > 8.0f) != 0ull) {
#pragma unroll
            for (int r = 0; r < 4; ++r) {
                float a = __builtin_amdgcn_exp2f(m_i[r] - mnew[r]);
                m_i[r] = mnew[r];
                l_i[r] *= a;
#pragma unroll
                for (int dt = 0; dt < 8; ++dt) oacc[dt][r] *= a;
            }
        }
        float psum[4] = {0.f, 0.f, 0.f, 0.f};
        // ---- half 0: P columns 0..63 ----
#pragma unroll
        for (int c4 = 0; c4 < 4; ++c4)
#pragma unroll
            for (int r = 0; r < 4; ++r) {
                float pv = __builtin_amdgcn_exp2f(sc[c4][r] - m_i[r]);
                psum[r] += pv;
                sP[wave][quad * 4 + r][c4 * 16 + lq] = f2b(pv);
            }
#pragma unroll
        for (int kc = 0; kc < 2; ++kc) {
            short8 pf = *(const short8*)(&sP[wave][lq][kc * 32 + quad * 8]);
#pragma unroll
            for (int dt = 0; dt < 8; ++dt) {
                short8 vf = kc == 0 ? vf00[dt]
                                    : *(const short8*)(Vs0 + (size_t)dt * 16 * 72 + 32);
                oacc[dt] = __builtin_amdgcn_mfma_f32_16x16x32_bf16(pf, vf, oacc[dt], 0, 0, 0);
            }
        }
        // ---- half 1: P columns 64..127 (sP reuse: same-wave DS order is safe) ----
#pragma unroll
        for (int c4 = 0; c4 < 4; ++c4)
#pragma unroll
            for (int r = 0; r < 4; ++r) {
                float pv = __builtin_amdgcn_exp2f(sc[4 + c4][r] - m_i[r]);
                psum[r] += pv;
                sP[wave][quad * 4 + r][c4 * 16 + lq] = f2b(pv);
            }
#pragma unroll
        for (int kc = 0; kc < 2; ++kc) {
            short8 pf = *(const short8*)(&sP[wave][lq][kc * 32 + quad * 8]);
#pragma unroll
            for (int dt = 0; dt < 8; ++dt) {
                short8 vf = *(const short8*)(Vs1 + (size_t)dt * 16 * 72 + kc * 32);
                oacc[dt] = __builtin_amdgcn_mfma_f32_16x16x32_bf16(pf, vf, oacc[dt], 0, 0, 0);
            }
        }
        // one shuffle-reduce per 128 kv (was per 64)
#pragma unroll
        for (int off = 8; off >= 1; off >>= 1)
#pragma unroll
            for (int r = 0; r < 4; ++r) psum[r] += __shfl_xor(psum[r], off);
#pragma unroll
        for (int r = 0; r < 4; ++r) l_i[r] += psum[r];
        __syncthreads();   // protect sK before next stage
    }
    float inv[4];
#pragma unroll
    for (int r = 0; r < 4; ++r) inv[r] = 1.f / l_i[r];
#pragma unroll
    for (int dt = 0; dt < 8; ++dt) {
#pragma unroll
        for (int r = 0; r < 4; ++r) {
            out[((size_t)(b * 2048 + myrow0 + r) * 16 + h) * 128 + dt * 16 + lq] =
                f2b(oacc[dt][r] * inv[r]);
        }
    }
}

// ---------- launch ----------
extern "C" void kernel_launch(void* const* d_in, const int* in_sizes, int n_in,
                              void* d_out, int out_size, void* d_ws, size_t ws_size,
                              hipStream_t stream) {
    const float* x     = (const float*)d_in[0];
    const float* freqs = (const float*)d_in[2];
    const float* wq_a  = (const float*)d_in[3];
    const float* qnw   = (const float*)d_in[4];
    const float* wq_b  = (const float*)d_in[5];
    const float* wkv_a = (const float*)d_in[6];
    const float* kvnw  = (const float*)d_in[7];
    const float* wkv_b = (const float*)d_in[8];
    const float* wo    = (const float*)d_in[9];

    char* ws = (char*)d_ws;
    size_t off = 0;
    auto alloc = [&](size_t n) { char* p = ws + off; off += (n + 255) & ~(size_t)255; return p; };
    ushort* xb    = (ushort*)alloc(4096ull * 2048 * 2);   // dead after fused a-gemm
    ushort* wqkva = (ushort*)alloc(2176ull * 2048 * 2);   // dead after fused a-gemm
    ushort* wqbb  = (ushort*)alloc(3072ull * 1536 * 2);   // dead after q_b gemm
    ushort* wkvbb = (ushort*)alloc(4096ull * 512 * 2);    // live until kv_b gemm
    ushort* wob   = (ushort*)alloc(2048ull * 2048 * 2);   // live until final gemm
    ushort* qakv  = (ushort*)alloc(4096ull * 2176 * 2);   // dead after q_b gemm
    ushort* kvc   = (ushort*)alloc(4096ull * 512 * 2);    // live until kv_b gemm
    ushort* kpe   = (ushort*)alloc(4096ull * 64 * 2);
    ushort* qfull = (ushort*)alloc(4096ull * 3072 * 2);
    ushort* kvbuf = (ushort*)alloc(4096ull * 4096 * 2);   // hosts Kfull (26.2 <= 33.6 MB)
    ushort* attno = (ushort*)alloc(4096ull * 2048 * 2);
    if (off > ws_size) return;
    ushort* Kfull = kvbuf;
    ushort* Vt = xb;   // Vt over xb+wqkva, both dead before kv_b gemm

    auto cvt = [&](const float* s, ushort* dd, int sr, int cols, size_t dtot, float scl) {
        int t4 = (int)(dtot / 4);
        cvt_pad<<<(t4 + 255) / 256, 256, 0, stream>>>(s, dd, sr, cols, t4, scl);
    };
    const float qk_scale = 1.44269504f / sqrtf(192.0f);
    cvt(x, xb, 4096, 2048, 4096ull * 2048, 1.f);
    cvt(wq_a, wqkva, 1536, 2048, 1536ull * 2048, 1.f);
    cvt(wkv_a, wqkva + 1536ull * 2048, 576, 2048, 640ull * 2048, 1.f);
    cvt(wq_b, wqbb, 3072, 1536, 3072ull * 1536, qk_scale);
    cvt(wkv_b, wkvbb, 4096, 512, 4096ull * 512, 1.f);
    cvt(wo, wob, 2048, 2048, 2048ull * 2048, 1.f);

    // fused q_a + kv_a projection (N=2176 not 256-divisible -> keep gemm_bt)
    gemm_bt<<<dim3(17, 32), 256, 0, stream>>>(xb, wqkva, qakv, 2048, 2048, 2048, 2176, 0, nullptr, nullptr);
    rmsnorm_inplace<<<4096, 256, 0, stream>>>(qakv, qnw, 1536, 2176);
    kvnorm_rope<<<4096, 256, 0, stream>>>(qakv + 1536, kvnw, freqs, kvc, kpe, 2176);
    // q_b projection: 4096x3072x1536 -> 8-phase template, 192 blocks
    gemm8p<<<dim3(192), 512, 0, stream>>>(qakv, wqbb, qfull, 1536, 2176, 1536, 3072, 0, 12);
    qrope<<<8192, 256, 0, stream>>>(qfull, freqs);
    kpe_fill<<<8192, 256, 0, stream>>>(kpe, Kfull);
    // kv_b gemm with fused scatter epilogue (keep gemm_bt)
    gemm_bt<<<dim3(32, 32), 256, 0, stream>>>(kvc, wkvbb, nullptr, 512, 512, 512, 0, 2, Kfull, Vt);
    mla_attn13<<<dim3(512), 512, 0, stream>>>(qfull, Kfull, Vt, attno);
    // out projection: 4096x2048x2048 f32 -> 8-phase template, 128 blocks
    gemm8p<<<dim3(128), 512, 0, stream>>>(attno, wob, (float*)d_out, 2048, 2048, 2048, 2048, 1, 8);
}

// Round 12
// 474.427 us; speedup vs baseline: 1.1006x; 1.0281x over previous
//
#include <hip/hip_runtime.h>
#include <math.h>

typedef short short8 __attribute__((ext_vector_type(8)));
typedef float float4v __attribute__((ext_vector_type(4)));
#define AS1 __attribute__((address_space(1)))
#define AS3 __attribute__((address_space(3)))

__device__ __forceinline__ float b2f(ushort u) {
    unsigned v = ((unsigned)u) << 16; float f; __builtin_memcpy(&f, &v, 4); return f;
}
__device__ __forceinline__ ushort f2b(float f) {
    unsigned v; __builtin_memcpy(&v, &f, 4);
    unsigned r = (v + 0x7fffu + ((v >> 16) & 1u)) >> 16;
    return (ushort)r;
}

// ---------- fp32 -> bf16 convert with optional scale (and zero-pad rows) ----------
__global__ void cvt_pad(const float* __restrict__ src, ushort* __restrict__ dst,
                        int src_rows, int cols, int total4, float scl) {
    int i = blockIdx.x * 256 + threadIdx.x;
    if (i >= total4) return;
    size_t e = (size_t)i * 4;
    int r = (int)(e / (size_t)cols);
    ushort4 o;
    if (r < src_rows) {
        float4 v = *(const float4*)(src + e);
        o.x = f2b(v.x * scl); o.y = f2b(v.y * scl); o.z = f2b(v.z * scl); o.w = f2b(v.w * scl);
    } else {
        o.x = 0; o.y = 0; o.z = 0; o.w = 0;
    }
    *(ushort4*)(dst + e) = o;
}

// ---------- 256x256 8-phase bf16 GEMM (T2 swizzle + T3/T4 counted vmcnt + T5) ----------
// C(MxN) = A(MxK) @ B(NxK)^T. Requires M%256==0, N%256==0 (B rows padded), K%128==0,
// grid%8==0. mode 0: bf16 C (guarded col<ncol); mode 1: f32 C (guarded);
// mode 2: MLA kv scatter (Kf nope cols + Vt transposed V) — port of gemm_bt's epilogue,
// layout-independent (pure function of row0/col/acc).
__device__ __forceinline__ short8 rdf(const ushort* base, int row, int kb) {
    int raw = row * 128 + kb;
    int off = raw ^ (((raw >> 9) & 1) << 5);
    return *(const short8*)((const char*)base + off);
}
__device__ __forceinline__ void stage_half(const ushort* __restrict__ G, int ldg,
                                           int row0, int k0, ushort* ldsbase,
                                           int wave, int lane) {
#pragma unroll
    for (int rr = 0; rr < 2; ++rr) {
        int x = rr * 8192 + wave * 1024 + lane * 16;   // this thread's linear dst byte
        int l = x ^ (((x >> 9) & 1) << 5);             // logical byte it must hold
        int r = l >> 7, c2 = l & 127;
        __builtin_amdgcn_global_load_lds(
            (const AS1 void*)(G + (size_t)(row0 + r) * ldg + k0 + (c2 >> 1)),
            (AS3 void*)((char*)ldsbase + rr * 8192 + wave * 1024), 16, 0, 0);
    }
}

#define GBAR() do { asm volatile("" ::: "memory"); __builtin_amdgcn_s_barrier(); } while (0)

#define PHASE(QD, SB, VMTAIL, ...) do {                                               \
    short8 a0  = rdf(&sA[SB][0], wm * 128 + (2 * (QD)) * 16 + lq, quad * 16);         \
    short8 a0k = rdf(&sA[SB][0], wm * 128 + (2 * (QD)) * 16 + lq, 64 + quad * 16);    \
    short8 a1  = rdf(&sA[SB][0], wm * 128 + (2 * (QD) + 1) * 16 + lq, quad * 16);     \
    short8 a1k = rdf(&sA[SB][0], wm * 128 + (2 * (QD) + 1) * 16 + lq, 64 + quad * 16);\
    if ((QD) == 0) {                                                                  \
        _Pragma("unroll")                                                             \
        for (int fc = 0; fc < 4; ++fc) {                                              \
            bF[fc][0] = rdf(&sB[SB][0], wn * 64 + fc * 16 + lq, quad * 16);           \
            bF[fc][1] = rdf(&sB[SB][0], wn * 64 + fc * 16 + lq, 64 + quad * 16);      \
        }                                                                             \
    }                                                                                 \
    __VA_ARGS__;                                                                      \
    GBAR();                                                                           \
    __builtin_amdgcn_s_setprio(1);                                                    \
    _Pragma("unroll")                                                                 \
    for (int fc = 0; fc < 4; ++fc) {                                                  \
        acc[2*(QD)][fc]   = __builtin_amdgcn_mfma_f32_16x16x32_bf16(a0,  bF[fc][0], acc[2*(QD)][fc],   0, 0, 0); \
        acc[2*(QD)][fc]   = __builtin_amdgcn_mfma_f32_16x16x32_bf16(a0k, bF[fc][1], acc[2*(QD)][fc],   0, 0, 0); \
        acc[2*(QD)+1][fc] = __builtin_amdgcn_mfma_f32_16x16x32_bf16(a1,  bF[fc][0], acc[2*(QD)+1][fc], 0, 0, 0); \
        acc[2*(QD)+1][fc] = __builtin_amdgcn_mfma_f32_16x16x32_bf16(a1k, bF[fc][1], acc[2*(QD)+1][fc], 0, 0, 0); \
    }                                                                                 \
    __builtin_amdgcn_s_setprio(0);                                                    \
    VMTAIL;                                                                           \
    GBAR();                                                                           \
} while (0)

__global__ __launch_bounds__(512, 2)
void gemm8p(const ushort* __restrict__ A, const ushort* __restrict__ B,
            void* __restrict__ Cv, int K, int lda, int ldb, int ldc, int mode,
            int nbn, int ncol, ushort* __restrict__ Kf, ushort* __restrict__ Vtp) {
    __shared__ ushort sA[2][256 * 64];
    __shared__ ushort sB[2][256 * 64];
    const int tid = threadIdx.x, wave = tid >> 6, lane = tid & 63;
    const int lq = lane & 15, quad = lane >> 4;
    const int wm = wave >> 2, wn = wave & 3;
    const int nwg = gridDim.x;
    const int wg = (blockIdx.x & 7) * (nwg >> 3) + (blockIdx.x >> 3);  // XCD swizzle
    const int bm = (wg / nbn) * 256, bn = (wg % nbn) * 256;

    ushort* sA0h0 = &sA[0][0];     ushort* sA0h1 = &sA[0][8192];
    ushort* sA1h0 = &sA[1][0];     ushort* sA1h1 = &sA[1][8192];
    ushort* sB0h0 = &sB[0][0];     ushort* sB0h1 = &sB[0][8192];
    ushort* sB1h0 = &sB[1][0];     ushort* sB1h1 = &sB[1][8192];

    float4v acc[8][4] = {};
    const int nkt = K >> 6;        // 64-wide K tiles (even; K%128==0)
    const int iters = nkt >> 1;

    // prologue: tile0 (A+B -> buf0), tile1 B -> buf1 (tile1 A staged in iter0 p1,p2)
    stage_half(A, lda, bm,       0, sA0h0, wave, lane);
    stage_half(A, lda, bm + 128, 0, sA0h1, wave, lane);
    stage_half(B, ldb, bn,       0, sB0h0, wave, lane);
    stage_half(B, ldb, bn + 128, 0, sB0h1, wave, lane);
    stage_half(B, ldb, bn,      64, sB1h0, wave, lane);
    stage_half(B, ldb, bn + 128,64, sB1h1, wave, lane);
    asm volatile("s_waitcnt vmcnt(4)" ::: "memory");   // tile0 landed; tile1-B in flight
    GBAR();

    for (int j = 0; j < iters; ++j) {
        const int t1 = 2 * j + 1, t2 = 2 * j + 2, t3 = 2 * j + 3;
        const bool lastj = (j == iters - 1);
        short8 bF[4][2];
        // phases 1-4: tile 2j from buf0
        PHASE(0, 0, (void)0, stage_half(A, lda, bm,       t1 * 64, sA1h0, wave, lane));
        PHASE(1, 0, (void)0, stage_half(A, lda, bm + 128, t1 * 64, sA1h1, wave, lane));
        PHASE(2, 0, (void)0, if (t2 < nkt) stage_half(B, ldb, bn,       t2 * 64, sB0h0, wave, lane));
        PHASE(3, 0,
              if (lastj) { asm volatile("s_waitcnt vmcnt(0)" ::: "memory"); }
              else       { asm volatile("s_waitcnt vmcnt(4)" ::: "memory"); },
              if (t2 < nkt) stage_half(B, ldb, bn + 128, t2 * 64, sB0h1, wave, lane));
        // phases 5-8: tile 2j+1 from buf1
        PHASE(0, 1, (void)0, if (t2 < nkt) stage_half(A, lda, bm,       t2 * 64, sA0h0, wave, lane));
        PHASE(1, 1, (void)0, if (t2 < nkt) stage_half(A, lda, bm + 128, t2 * 64, sA0h1, wave, lane));
        PHASE(2, 1, (void)0, if (t3 < nkt) stage_half(B, ldb, bn,       t3 * 64, sB1h0, wave, lane));
        PHASE(3, 1,
              if (lastj) { asm volatile("s_waitcnt vmcnt(0)" ::: "memory"); }
              else       { asm volatile("s_waitcnt vmcnt(4)" ::: "memory"); },
              if (t3 < nkt) stage_half(B, ldb, bn + 128, t3 * 64, sB1h1, wave, lane));
    }

#pragma unroll
    for (int fr = 0; fr < 8; ++fr) {
        int row0 = bm + wm * 128 + fr * 16 + quad * 4;
#pragma unroll
        for (int fc = 0; fc < 4; ++fc) {
            int col = bn + wn * 64 + fc * 16 + lq;
            if (mode == 0) {
                if (col < ncol) {
                    ushort* C = (ushort*)Cv;
#pragma unroll
                    for (int r = 0; r < 4; ++r)
                        C[(size_t)(row0 + r) * ldc + col] = f2b(acc[fr][fc][r]);
                }
            } else if (mode == 1) {
                if (col < ncol) {
                    float* C = (float*)Cv;
#pragma unroll
                    for (int r = 0; r < 4; ++r)
                        C[(size_t)(row0 + r) * ldc + col] = acc[fr][fc][r];
                }
            } else {
                // MLA kv scatter: col = h*256 + c; c<128 -> Kfull nope, else Vt transposed
                int h = col >> 8, c = col & 255;
                int bh = ((row0 >> 11) << 4) + h;
                if (c < 128) {
#pragma unroll
                    for (int r = 0; r < 4; ++r) {
                        int s = (row0 + r) & 2047;
                        Kf[((size_t)bh * 2048 + s) * 200 + c] = f2b(acc[fr][fc][r]);
                    }
                } else {
                    int d = c - 128;
                    int kt = (row0 & 2047) >> 6, kv = row0 & 63;
                    ushort4 o;
                    o.x = f2b(acc[fr][fc][0]); o.y = f2b(acc[fr][fc][1]);
                    o.z = f2b(acc[fr][fc][2]); o.w = f2b(acc[fr][fc][3]);
                    *(ushort4*)(Vtp + (((size_t)bh * 32 + kt) * 128 + d) * 72 + kv) = o;
                }
            }
        }
    }
}

// ---------- rmsnorm (in-place, one block per row, strided) ----------
__global__ void rmsnorm_inplace(ushort* __restrict__ d, const float* __restrict__ w,
                                int cols, int ld) {
    int row = blockIdx.x, tid = threadIdx.x;
    ushort* p = d + (size_t)row * ld;
    float ss = 0.f;
    for (int i = tid; i < cols; i += 256) { float v = b2f(p[i]); ss += v * v; }
#pragma unroll
    for (int off = 32; off >= 1; off >>= 1) ss += __shfl_xor(ss, off);
    __shared__ float red[4];
    if ((tid & 63) == 0) red[tid >> 6] = ss;
    __syncthreads();
    float tot = red[0] + red[1] + red[2] + red[3];
    float rs = rsqrtf(tot / (float)cols + 1e-6f);
    for (int i = tid; i < cols; i += 256) p[i] = f2b(b2f(p[i]) * rs * w[i]);
}

// ---------- kv norm (cols 0..512) + k_pe rope (cols 512..576), strided ----------
__global__ void kvnorm_rope(const ushort* __restrict__ kvraw, const float* __restrict__ w,
                            const float* __restrict__ freqs, ushort* __restrict__ kvc,
                            ushort* __restrict__ kpe, int ld) {
    int row = blockIdx.x, tid = threadIdx.x;
    int s = row & 2047;
    const ushort* p = kvraw + (size_t)row * ld;
    float v0 = b2f(p[tid]), v1 = b2f(p[tid + 256]);
    float ss = v0 * v0 + v1 * v1;
#pragma unroll
    for (int off = 32; off >= 1; off >>= 1) ss += __shfl_xor(ss, off);
    __shared__ float red[4];
    if ((tid & 63) == 0) red[tid >> 6] = ss;
    __syncthreads();
    float tot = red[0] + red[1] + red[2] + red[3];
    float rs = rsqrtf(tot / 512.f + 1e-6f);
    kvc[(size_t)row * 512 + tid] = f2b(v0 * rs * w[tid]);
    kvc[(size_t)row * 512 + tid + 256] = f2b(v1 * rs * w[tid + 256]);
    if (tid < 32) {
        float re = b2f(p[512 + 2 * tid]), im = b2f(p[512 + 2 * tid + 1]);
        float cs = freqs[(s * 32 + tid) * 2], sn = freqs[(s * 32 + tid) * 2 + 1];
        kpe[(size_t)row * 64 + 2 * tid] = f2b(re * cs - im * sn);
        kpe[(size_t)row * 64 + 2 * tid + 1] = f2b(re * sn + im * cs);
    }
}

// ---------- rope on q_pe (last 64 of each 192-dim head) ----------
__global__ void qrope(ushort* __restrict__ q, const float* __restrict__ freqs) {
    int idx = blockIdx.x * 256 + threadIdx.x;
    int i = idx & 31;
    int h = (idx >> 5) & 15;
    int srow = idx >> 9;
    int s = srow & 2047;
    ushort* p = q + ((size_t)srow * 16 + h) * 192 + 128 + 2 * i;
    float re = b2f(p[0]), im = b2f(p[1]);
    float cs = freqs[(s * 32 + i) * 2], sn = freqs[(s * 32 + i) * 2 + 1];
    p[0] = f2b(re * cs - im * sn);
    p[1] = f2b(re * sn + im * cs);
}

// ---------- fill roped k_pe into Kfull cols 128..191 (broadcast over h) ----------
__global__ void kpe_fill(const ushort* __restrict__ kpe, ushort* __restrict__ Kfull) {
    int tid = threadIdx.x;
    int row = blockIdx.x * 8 + (tid >> 5);   // row = bh*2048 + s
    int c = tid & 31;
    int bh = row >> 11, s = row & 2047, b = bh >> 4;
    ushort2 v;
    v.x = kpe[((size_t)b * 2048 + s) * 64 + 2 * c];
    v.y = kpe[((size_t)b * 2048 + s) * 64 + 2 * c + 1];
    *(ushort2*)(Kfull + (size_t)row * 200 + 128 + 2 * c) = v;
}

// ---------- causal flash attention: R6 schedule, KVBLK=128 (proven 105.9us, R11) ----------
__global__ __launch_bounds__(512, 2)
void mla_attn13(const ushort* __restrict__ q, const ushort* __restrict__ Kfull,
                const ushort* __restrict__ Vt, ushort* __restrict__ out) {
    __shared__ ushort sK[128 * 200];
    __shared__ ushort sP[8][16][72];
    const int tid = threadIdx.x, wave = tid >> 6, lane = tid & 63;
    const int lq = lane & 15, quad = lane >> 4;
    const int lin = blockIdx.x;
    const int e = lin & 7, idx = lin >> 3;
    const int st = 15 - (idx >> 2);          // 128-row q super-tile, big first
    const int bh = e + 8 * (idx & 3);        // XCD-pinned: bh%8 == lin%8
    const int b = bh >> 4, h = bh & 15;
    const ushort* Kb = Kfull + (size_t)bh * 2048 * 200;
    const ushort* Vb = Vt + (size_t)bh * 32 * 128 * 72;

    const int qrow = st * 128 + wave * 16 + lq;
    const ushort* qp = q + ((size_t)(b * 2048 + qrow) * 16 + h) * 192 + quad * 8;
    short8 qf[6];
#pragma unroll
    for (int c = 0; c < 6; ++c) qf[c] = *(const short8*)(qp + c * 32);

    float4v oacc[8] = {};
    float m_i[4] = {-INFINITY, -INFINITY, -INFINITY, -INFINITY};
    float l_i[4] = {0.f, 0.f, 0.f, 0.f};
    const int myrow0 = st * 128 + wave * 16 + quad * 4;

    for (int kt = 0; kt <= st; ++kt) {
        // stage 128x200 K tile (3200 16B-chunks) across all 512 threads
        const ushort* Ksrc = Kb + (size_t)kt * 128 * 200;
#pragma unroll
        for (int i = 0; i < 7; ++i) {
            int cb = i * 512 + wave * 64;    // wave-uniform chunk base
            if (cb < 3200)
                __builtin_amdgcn_global_load_lds((const AS1 void*)(Ksrc + (size_t)(cb + lane) * 8),
                                                 (AS3 void*)(sK + cb * 8), 16, 0, 0);
        }
        __syncthreads();
        // V subtiles for this 128-kv tile (Vt is stored in 64-kv units)
        const ushort* Vs0 = Vb + (size_t)(2 * kt) * 128 * 72 + (size_t)lq * 72 + quad * 8;
        const ushort* Vs1 = Vs0 + 128 * 72;
        // S = Q K^T (per wave: 16 x 128)
        float4v sc[8];
#pragma unroll
        for (int ct = 0; ct < 8; ++ct) {
            float4v a = {0.f, 0.f, 0.f, 0.f};
#pragma unroll
            for (int c = 0; c < 6; ++c) {
                short8 kf = *(const short8*)(sK + (ct * 16 + lq) * 200 + c * 32 + quad * 8);
                a = __builtin_amdgcn_mfma_f32_16x16x32_bf16(qf[c], kf, a, 0, 0, 0);
            }
            sc[ct] = a;
        }
        // hoist V loads for half0/kc0 from L2: independent, fly during softmax
        short8 vf00[8];
#pragma unroll
        for (int dt = 0; dt < 8; ++dt)
            vf00[dt] = *(const short8*)(Vs0 + (size_t)dt * 16 * 72);
        // causal mask (branchless; only the diagonal tile actually masks) + max
        float mnew[4];
#pragma unroll
        for (int r = 0; r < 4; ++r) mnew[r] = m_i[r];
#pragma unroll
        for (int ct = 0; ct < 8; ++ct)
#pragma unroll
            for (int r = 0; r < 4; ++r) {
                float v = (kt * 128 + ct * 16 + lq) > (myrow0 + r) ? -INFINITY : sc[ct][r];
                sc[ct][r] = v;
                mnew[r] = fmaxf(mnew[r], v);
            }
#pragma unroll
        for (int off = 8; off >= 1; off >>= 1)
#pragma unroll
            for (int r = 0; r < 4; ++r) mnew[r] = fmaxf(mnew[r], __shfl_xor(mnew[r], off));
        // defer-max: rescale only if the max grew by > 8 (log2 domain)
        float g = mnew[0] - m_i[0];
#pragma unroll
        for (int r = 1; r < 4; ++r) g = fmaxf(g, mnew[r] - m_i[r]);
        if (__ballot(g > 8.0f) != 0ull) {
#pragma unroll
            for (int r = 0; r < 4; ++r) {
                float a = __builtin_amdgcn_exp2f(m_i[r] - mnew[r]);
                m_i[r] = mnew[r];
                l_i[r] *= a;
#pragma unroll
                for (int dt = 0; dt < 8; ++dt) oacc[dt][r] *= a;
            }
        }
        float psum[4] = {0.f, 0.f, 0.f, 0.f};
        // ---- half 0: P columns 0..63 ----
#pragma unroll
        for (int c4 = 0; c4 < 4; ++c4)
#pragma unroll
            for (int r = 0; r < 4; ++r) {
                float pv = __builtin_amdgcn_exp2f(sc[c4][r] - m_i[r]);
                psum[r] += pv;
                sP[wave][quad * 4 + r][c4 * 16 + lq] = f2b(pv);
            }
#pragma unroll
        for (int kc = 0; kc < 2; ++kc) {
            short8 pf = *(const short8*)(&sP[wave][lq][kc * 32 + quad * 8]);
#pragma unroll
            for (int dt = 0; dt < 8; ++dt) {
                short8 vf = kc == 0 ? vf00[dt]
                                    : *(const short8*)(Vs0 + (size_t)dt * 16 * 72 + 32);
                oacc[dt] = __builtin_amdgcn_mfma_f32_16x16x32_bf16(pf, vf, oacc[dt], 0, 0, 0);
            }
        }
        // ---- half 1: P columns 64..127 (sP reuse: same-wave DS order is safe) ----
#pragma unroll
        for (int c4 = 0; c4 < 4; ++c4)
#pragma unroll
            for (int r = 0; r < 4; ++r) {
                float pv = __builtin_amdgcn_exp2f(sc[4 + c4][r] - m_i[r]);
                psum[r] += pv;
                sP[wave][quad * 4 + r][c4 * 16 + lq] = f2b(pv);
            }
#pragma unroll
        for (int kc = 0; kc < 2; ++kc) {
            short8 pf = *(const short8*)(&sP[wave][lq][kc * 32 + quad * 8]);
#pragma unroll
            for (int dt = 0; dt < 8; ++dt) {
                short8 vf = *(const short8*)(Vs1 + (size_t)dt * 16 * 72 + kc * 32);
                oacc[dt] = __builtin_amdgcn_mfma_f32_16x16x32_bf16(pf, vf, oacc[dt], 0, 0, 0);
            }
        }
        // one shuffle-reduce per 128 kv (was per 64)
#pragma unroll
        for (int off = 8; off >= 1; off >>= 1)
#pragma unroll
            for (int r = 0; r < 4; ++r) psum[r] += __shfl_xor(psum[r], off);
#pragma unroll
        for (int r = 0; r < 4; ++r) l_i[r] += psum[r];
        __syncthreads();   // protect sK before next stage
    }
    float inv[4];
#pragma unroll
    for (int r = 0; r < 4; ++r) inv[r] = 1.f / l_i[r];
#pragma unroll
    for (int dt = 0; dt < 8; ++dt) {
#pragma unroll
        for (int r = 0; r < 4; ++r) {
            out[((size_t)(b * 2048 + myrow0 + r) * 16 + h) * 128 + dt * 16 + lq] =
                f2b(oacc[dt][r] * inv[r]);
        }
    }
}

// ---------- launch ----------
extern "C" void kernel_launch(void* const* d_in, const int* in_sizes, int n_in,
                              void* d_out, int out_size, void* d_ws, size_t ws_size,
                              hipStream_t stream) {
    const float* x     = (const float*)d_in[0];
    const float* freqs = (const float*)d_in[2];
    const float* wq_a  = (const float*)d_in[3];
    const float* qnw   = (const float*)d_in[4];
    const float* wq_b  = (const float*)d_in[5];
    const float* wkv_a = (const float*)d_in[6];
    const float* kvnw  = (const float*)d_in[7];
    const float* wkv_b = (const float*)d_in[8];
    const float* wo    = (const float*)d_in[9];

    char* ws = (char*)d_ws;
    size_t off = 0;
    auto alloc = [&](size_t n) { char* p = ws + off; off += (n + 255) & ~(size_t)255; return p; };
    ushort* xb    = (ushort*)alloc(4096ull * 2048 * 2);   // dead after fused a-gemm
    ushort* wqkva = (ushort*)alloc(2304ull * 2048 * 2);   // 2304 rows (N-pad to 9x256); dead after a-gemm
    ushort* wqbb  = (ushort*)alloc(3072ull * 1536 * 2);   // dead after q_b gemm
    ushort* wkvbb = (ushort*)alloc(4096ull * 512 * 2);    // live until kv_b gemm
    ushort* wob   = (ushort*)alloc(2048ull * 2048 * 2);   // live until final gemm
    ushort* qakv  = (ushort*)alloc(4096ull * 2176 * 2);   // dead after q_b gemm
    ushort* kvc   = (ushort*)alloc(4096ull * 512 * 2);    // live until kv_b gemm
    ushort* kpe   = (ushort*)alloc(4096ull * 64 * 2);
    ushort* qfull = (ushort*)alloc(4096ull * 3072 * 2);
    ushort* kvbuf = (ushort*)alloc(4096ull * 4096 * 2);   // hosts Kfull (26.2 <= 33.6 MB)
    ushort* attno = (ushort*)alloc(4096ull * 2048 * 2);
    if (off > ws_size) return;
    ushort* Kfull = kvbuf;
    ushort* Vt = xb;   // Vt (18.9MB) over xb+wqkva (26.2MB), both dead before kv_b gemm

    auto cvt = [&](const float* s, ushort* dd, int sr, int cols, size_t dtot, float scl) {
        int t4 = (int)(dtot / 4);
        cvt_pad<<<(t4 + 255) / 256, 256, 0, stream>>>(s, dd, sr, cols, t4, scl);
    };
    const float qk_scale = 1.44269504f / sqrtf(192.0f);
    cvt(x, xb, 4096, 2048, 4096ull * 2048, 1.f);
    cvt(wq_a, wqkva, 1536, 2048, 1536ull * 2048, 1.f);
    // wkv_a: 576 real rows, zero-pad through row 768 (global rows 1536..2303)
    cvt(wkv_a, wqkva + 1536ull * 2048, 576, 2048, 768ull * 2048, 1.f);
    cvt(wq_b, wqbb, 3072, 1536, 3072ull * 1536, qk_scale);
    cvt(wkv_b, wkvbb, 4096, 512, 4096ull * 512, 1.f);
    cvt(wo, wob, 2048, 2048, 2048ull * 2048, 1.f);

    // fused q_a + kv_a projection: 4096 x (2176 of 2304) x 2048, 8-phase, 144 blocks
    // (B padded to 2304 rows; stores guarded to col < 2176; qakv layout unchanged)
    gemm8p<<<dim3(144), 512, 0, stream>>>(xb, wqkva, qakv, 2048, 2048, 2048, 2176, 0, 9, 2176, nullptr, nullptr);
    rmsnorm_inplace<<<4096, 256, 0, stream>>>(qakv, qnw, 1536, 2176);
    kvnorm_rope<<<4096, 256, 0, stream>>>(qakv + 1536, kvnw, freqs, kvc, kpe, 2176);
    // q_b projection: 4096x3072x1536 -> 8-phase template, 192 blocks
    gemm8p<<<dim3(192), 512, 0, stream>>>(qakv, wqbb, qfull, 1536, 2176, 1536, 3072, 0, 12, 3072, nullptr, nullptr);
    qrope<<<8192, 256, 0, stream>>>(qfull, freqs);
    kpe_fill<<<8192, 256, 0, stream>>>(kpe, Kfull);
    // kv_b gemm with fused scatter epilogue: 4096x4096x512, 8-phase, 256 blocks
    gemm8p<<<dim3(256), 512, 0, stream>>>(kvc, wkvbb, nullptr, 512, 512, 512, 0, 2, 16, 0, Kfull, Vt);
    mla_attn13<<<dim3(512), 512, 0, stream>>>(qfull, Kfull, Vt, attno);
    // out projection: 4096x2048x2048 f32 -> 8-phase template, 128 blocks
    gemm8p<<<dim3(128), 512, 0, stream>>>(attno, wob, (float*)d_out, 2048, 2048, 2048, 2048, 1, 8, 2048, nullptr, nullptr);
}